// Round 5
// baseline (1332.674 us; speedup 1.0000x reference)
//
#include <hip/hip_runtime.h>
#include <math.h>

__device__ const int d_PERM[9] = {0,2,6,3,7,1,5,8,4};
__device__ const int d_DEG[9]  = {0,1,1,1,2,2,2,2,2};

__device__ __forceinline__ float silu_f(float x){ return x / (1.0f + __expf(-x)); }

// flag: 0 = int32 words, 1 = u8 bytes, 2 = float32 words, 3 = int64 (low word)
__device__ __forceinline__ int mask_at(const void* mp, int flag, int e){
  if (flag==1) return ((const unsigned char*)mp)[e] != 0;
  if (flag==3) return ((const unsigned int*)mp)[2*e] != 0u;
  return ((const unsigned int*)mp)[e] != 0u;
}

__global__ void k_detect(const unsigned int* __restrict__ w, int* __restrict__ flag){
  __shared__ int notI, notF, anyOdd, anyEven;
  if (threadIdx.x==0){ notI=0; notF=0; anyOdd=0; anyEven=0; }
  __syncthreads();
  int li=0, lf=0, lo=0, le=0;
  for (int i = threadIdx.x; i < 1024; i += 256){
    unsigned int v = w[i];
    if (v != 0u && v != 1u) li = 1;
    if (v != 0u && v != 0x3F800000u) lf = 1;
    if (v != 0u){ if (i & 1) lo = 1; else le = 1; }
  }
  if (li) atomicOr(&notI,1);
  if (lf) atomicOr(&notF,1);
  if (lo) atomicOr(&anyOdd,1);
  if (le) atomicOr(&anyEven,1);
  __syncthreads();
  if (threadIdx.x==0){
    int f;
    if (!notI) f = (anyOdd || !anyEven) ? 0 : 3;
    else       f = (!notF) ? 2 : 1;
    *flag = f;
  }
}

// ---------------- precompute H = x @ w_in[DEG] (+b_in at j==0), layout (N,9,128) ----------------
__global__ __launch_bounds__(128) void k_h(const float* __restrict__ x,
    const float* __restrict__ w_in, const float* __restrict__ b_in,
    float* __restrict__ H){
  __shared__ float xl[16][260];
  int i = blockIdx.y; int n0 = blockIdx.x*16;
  int deg = d_DEG[i];
  for (int idx = threadIdx.x; idx < 16*256; idx += 128){
    int r = idx >> 8, c = idx & 255;
    xl[r][c] = x[((size_t)(n0+r)*9 + i)*256 + c];
  }
  __syncthreads();
  int o = threadIdx.x;
  float acc[16];
  #pragma unroll
  for (int r=0;r<16;r++) acc[r]=0.f;
  const float* w = w_in + (size_t)deg*32768 + o;
  for (int c=0;c<256;c+=4){
    float w0=w[(size_t)c*128], w1=w[(size_t)(c+1)*128], w2=w[(size_t)(c+2)*128], w3=w[(size_t)(c+3)*128];
    #pragma unroll
    for (int r=0;r<16;r++){
      float4 xv4 = *(const float4*)&xl[r][c];
      acc[r] += xv4.x*w0 + xv4.y*w1 + xv4.z*w2 + xv4.w*w3;
    }
  }
  float bb = (i==0)? b_in[o] : 0.f;
  #pragma unroll
  for (int r=0;r<16;r++) H[((size_t)(n0+r)*9+i)*128+o] = acc[r]+bb;
}

// ---------------- precompute XE (E,16) ----------------
__global__ __launch_bounds__(256) void k_xe(const float* __restrict__ attn,
    const float* __restrict__ fdw, const float* __restrict__ fdb,
    const float* __restrict__ few, const float* __restrict__ feb,
    const float* __restrict__ es, const float* __restrict__ et,
    const int* __restrict__ an, const int* __restrict__ esrc,
    float* __restrict__ XE){
  int e = blockIdx.x*256 + threadIdx.x;
  float aw[32];
  #pragma unroll
  for (int k=0;k<32;k+=4){
    float4 v = *(const float4*)&attn[(size_t)e*32+k];
    aw[k]=v.x; aw[k+1]=v.y; aw[k+2]=v.z; aw[k+3]=v.w;
  }
  int src = esrc[e]; int tgt = e>>3;
  int za = an[src], zb = an[tgt];
  float v0[16];
  #pragma unroll
  for (int j=0;j<16;j++){
    float s = fdb[j] + es[(size_t)za*16+j] + et[(size_t)zb*16+j];
    #pragma unroll
    for (int k=0;k<32;k++) s += aw[k]*fdw[k*16+j];
    v0[j] = silu_f(s);
  }
  #pragma unroll
  for (int j=0;j<16;j++){
    float s = feb[j];
    #pragma unroll
    for (int k=0;k<16;k++) s += v0[k]*few[k*16+j];
    XE[(size_t)e*16+j] = silu_f(s);
  }
}

// ---- dot helpers (K compile-time at call sites; weights column-strided 128) ----
__device__ __forceinline__ float dotW(const float* __restrict__ A, const float* __restrict__ Wm, int K){
  float s = 0.f;
  #pragma unroll 4
  for (int i=0;i<K;i+=4){
    float4 a = *(const float4*)&A[i];
    s += a.x*Wm[(size_t)i*128] + a.y*Wm[(size_t)(i+1)*128]
       + a.z*Wm[(size_t)(i+2)*128] + a.w*Wm[(size_t)(i+3)*128];
  }
  return s;
}
__device__ __forceinline__ float dot2W(const float* __restrict__ P0, const float* __restrict__ P1,
    const float* __restrict__ W0, const float* __restrict__ W1, int ldw){
  float s = 0.f;
  #pragma unroll 4
  for (int k=0;k<128;k+=4){
    float4 a = *(const float4*)&P0[k];
    float4 b = *(const float4*)&P1[k];
    s += a.x*W0[(size_t)k*ldw] + a.y*W0[(size_t)(k+1)*ldw] + a.z*W0[(size_t)(k+2)*ldw] + a.w*W0[(size_t)(k+3)*ldw];
    s += b.x*W1[(size_t)k*ldw] + b.y*W1[(size_t)(k+1)*ldw] + b.z*W1[(size_t)(k+2)*ldw] + b.w*W1[(size_t)(k+3)*ldw];
  }
  return s;
}

// ---------------- mega kernel: one block per atom ----------------
// LDS layout (floats): acc 0..1152 | xs 1152..2304, xt 2304..3456 (Zb aliases 1152..3456)
//   gg 3456..4736 (Yb aliases 3456..4608) | P 4736..7040 | wl 7040..7121 | xe16 7124..7140 | xv 7140..7156
__global__ __launch_bounds__(256) void k_mega(
    const float* __restrict__ x,      const float* __restrict__ w_in,  const float* __restrict__ b_in,
    const float* __restrict__ attn,
    const float* __restrict__ fdw,    const float* __restrict__ fdb,
    const float* __restrict__ few,    const float* __restrict__ feb,
    const float* __restrict__ es,     const float* __restrict__ et,
    const int*   __restrict__ an,     const int*   __restrict__ esrc,
    const float* __restrict__ d0w,    const float* __restrict__ d0b,
    const float* __restrict__ m1dw,   const float* __restrict__ m1db,
    const float* __restrict__ m2dw,   const float* __restrict__ m2db,
    const float* __restrict__ m0w1,   const float* __restrict__ m0w2,
    const float* __restrict__ m1w1r,  const float* __restrict__ m1w2r,
    const float* __restrict__ m1w1i,  const float* __restrict__ m1w2i,
    const float* __restrict__ m2w1r,  const float* __restrict__ m2w2r,
    const float* __restrict__ m2w1i,  const float* __restrict__ m2w2i,
    const float* __restrict__ wig,    const float* __restrict__ tg,   const float* __restrict__ fg,
    const float* __restrict__ w_out,  const float* __restrict__ b_out,
    const void*  __restrict__ maskp,  const int* __restrict__ flagp,
    const float* __restrict__ Hg,     const float* __restrict__ XEg,  int pre,
    float* __restrict__ out)
{
  __shared__ float S[7168];
  float* acc  = S;
  float* xs   = S + 1152;
  float* xtl  = S + 2304;
  float* Zb   = S + 1152;
  float* gg   = S + 3456;
  float* Yb   = S + 3456;
  float* P    = S + 4736;
  float* wl   = S + 7040;
  float* xe16 = S + 7124;
  float* xv   = S + 7140;

  const int n   = blockIdx.x;
  const int tid = threadIdx.x;
  const int f   = *flagp;

  for (int i = tid; i < 1152; i += 256) acc[i] = 0.f;

  for (int k = 0; k < 8; k++){
    int e = n*8 + k;
    if (mask_at(maskp, f, e)) continue;
    int src = esrc[e];

    __syncthreads();   // previous iteration done with Zb/wl

    if (pre){
      // ---- A2: stage wl & xe; rotate from precomputed H ----
      for (int i = tid; i < 81; i += 256) wl[i] = wig[(size_t)e*81 + i];
      if (tid < 16) xe16[tid] = XEg[(size_t)e*16 + tid];
      for (int idx = tid; idx < 1152; idx += 256){
        int p = idx >> 7, c = idx & 127;
        int ch = d_PERM[p];
        const float* wr = wig + (size_t)e*81 + ch*9;
        const float* hs = Hg + (size_t)src*1152 + c;
        const float* ht = Hg + (size_t)n*1152 + c;
        float s1 = 0.f, s2 = 0.f;
        #pragma unroll
        for (int j = 0; j < 9; j++){
          float wv = wr[j];
          s1 += wv * hs[j*128];
          s2 += wv * ht[j*128];
        }
        xs[idx]  = s1;
        xtl[idx] = s2;
      }
    } else {
      // ---- F1: wl, xv, hsrc->P[0..1152), htgt->P[1152..2304) ----
      for (int i = tid; i < 81; i += 256) wl[i] = wig[(size_t)e*81 + i];
      if (tid < 16){
        int j = tid;
        float s = fdb[j] + es[(size_t)an[src]*16 + j] + et[(size_t)an[n]*16 + j];
        for (int kk = 0; kk < 32; kk++) s += attn[(size_t)e*32 + kk] * fdw[kk*16 + j];
        xv[j] = silu_f(s);
      }
      for (int idx = tid; idx < 2304; idx += 256){
        int which = idx >= 1152;
        int lidx = idx - which*1152;
        int j = lidx >> 7, c = lidx & 127;
        int deg = d_DEG[j];
        const float* wp = w_in + (size_t)deg*32768 + c;
        const float* xp = x + ((size_t)(which ? n : src)*9 + j)*256;
        float s = (j==0) ? b_in[c] : 0.f;
        for (int cc = 0; cc < 256; cc++) s += xp[cc] * wp[cc*128];
        P[idx] = s;
      }
      __syncthreads();
      // ---- F2: xe16; rotate from P ----
      if (tid < 16){
        int j = tid;
        float s = feb[j];
        for (int kk = 0; kk < 16; kk++) s += xv[kk] * few[kk*16 + j];
        xe16[j] = silu_f(s);
      }
      for (int idx = tid; idx < 1152; idx += 256){
        int p = idx >> 7, c = idx & 127;
        int ch = d_PERM[p];
        float s1 = 0.f, s2 = 0.f;
        #pragma unroll
        for (int j = 0; j < 9; j++){
          float wv = wl[ch*9 + j];
          s1 += wv * P[j*128 + c];
          s2 += wv * P[1152 + j*128 + c];
        }
        xs[idx]  = s1;
        xtl[idx] = s2;
      }
    }
    __syncthreads();

    // ---- A3: gates gg[1280] ----
    for (int col = tid; col < 1280; col += 256){
      int b = col / 640, r = col % 640;
      const float* w; float bias; int ldw, c2;
      if (r < 128){       w = d0w  + (size_t)b*2048; c2 = r;     ldw = 128; bias = d0b[b*128 + c2]; }
      else if (r < 384){  w = m1dw + (size_t)b*4096; c2 = r-128; ldw = 256; bias = m1db[b*256 + c2]; }
      else {              w = m2dw + (size_t)b*4096; c2 = r-384; ldw = 256; bias = m2db[b*256 + c2]; }
      float s = bias;
      #pragma unroll
      for (int kk = 0; kk < 16; kk++) s += xe16[kk] * w[kk*ldw + c2];
      gg[col] = silu_f(s);
    }
    __syncthreads();

    // ---- A4: stage-1 P ----
    for (int o = tid; o < 2304; o += 256){
      float s;
      if (o < 256){
        int path = o >> 7, h = o & 127;
        s = dotW(path ? xtl : xs, m0w1 + (size_t)path*49152 + h, 384);
      } else if (o < 1280){
        int q = (o-256) >> 8; int rem = (o-256) & 255; int t = rem >> 7, h = rem & 127;
        const float* A  = ((q>=2) ? xtl : xs) + 384 + t*256;
        const float* Wm = ((q&1) ? m1w1i : m1w1r) + (size_t)((q>=2)?1:0)*32768 + h;
        s = dotW(A, Wm, 256);
      } else {
        int q = (o-1280) >> 8; int rem = (o-1280) & 255; int t = rem >> 7, h = rem & 127;
        const float* A  = ((q>=2) ? xtl : xs) + 896 + t*128;
        const float* Wm = ((q&1) ? m2w1i : m2w1r) + (size_t)((q>=2)?1:0)*16384 + h;
        s = dotW(A, Wm, 128);
      }
      P[o] = s;
    }
    __syncthreads();

    // ---- A5: gate P in place ----
    for (int o = tid; o < 2304; o += 256){
      int h = o & 127, goff;
      if (o < 256) goff = (o >> 7) ? 640 : 0;
      else if (o < 1280){ int q = (o-256) >> 8;  goff = 128 + (q&1)*128 + (q>>1)*640; }
      else              { int q = (o-1280) >> 8; goff = 384 + (q&1)*128 + (q>>1)*640; }
      P[o] *= gg[goff + h];
    }
    __syncthreads();

    // ---- A6: stage-2 -> Yb (orig channel order) ----
    for (int o = tid; o < 1152; o += 256){
      float s; int ch, c;
      if (o < 384){
        int g = o >> 7; c = o & 127;
        ch = (g==0) ? 0 : ((g==1) ? 2 : 6);
        const float* w0 = m0w2 + o;                  // (2,128,384)
        s = dot2W(P, P+128, w0, w0+49152, 384);
      } else if (o < 896){
        int om = o - 384; int tp = om >> 8; int col = om & 255;
        int g = col >> 7; c = col & 127;
        ch = tp ? (g ? 5 : 1) : (g ? 7 : 3);
        float sgn = tp ? 1.f : -1.f;
        const float* wr = m1w2r + col;               // (2,128,256)
        const float* wi = m1w2i + col;
        s = dot2W(P+256+tp*128,     P+768+tp*128,     wr, wr+32768, 256)
          + sgn * dot2W(P+512+(1-tp)*128, P+1024+(1-tp)*128, wi, wi+32768, 256);
      } else {
        int om = o - 896; int tp = om >> 7; c = om & 127;
        ch = tp ? 4 : 8;
        float sgn = tp ? 1.f : -1.f;
        const float* wr = m2w2r + c;                 // (2,128,128)
        const float* wi = m2w2i + c;
        s = dot2W(P+1280+tp*128,     P+1792+tp*128,     wr, wr+16384, 128)
          + sgn * dot2W(P+1536+(1-tp)*128, P+2048+(1-tp)*128, wi, wi+16384, 128);
      }
      Yb[ch*128 + c] = s;
    }
    __syncthreads();

    // ---- A7: grid (to_grid -> silu -> from_grid) ----
    {
      int half = tid >> 7, c = tid & 127;
      float z[9];
      #pragma unroll
      for (int i = 0; i < 9; i++) z[i] = 0.f;
      float y[9];
      #pragma unroll
      for (int i = 0; i < 9; i++) y[i] = Yb[i*128 + c];
      int p0 = half*162, p1 = p0 + 162;
      #pragma unroll 2
      for (int p = p0; p < p1; p++){
        float gp = 0.f;
        #pragma unroll
        for (int i = 0; i < 9; i++) gp += tg[p*9 + i] * y[i];
        float s = silu_f(gp);
        #pragma unroll
        for (int i = 0; i < 9; i++) z[i] += fg[p*9 + i] * s;
      }
      __syncthreads();   // Yb (alias region with nothing) safe; ensures all read Yb before Zb write? different regions; barrier protects Zb vs xs? Zb aliases xs/xtl (dead) -> ok; keep for A8 ordering
      #pragma unroll
      for (int i = 0; i < 9; i++) Zb[half*1152 + i*128 + c] = z[i];
    }
    __syncthreads();

    // ---- A8: final wigner-transpose, accumulate ----
    for (int idx = tid; idx < 1152; idx += 256){
      int i2 = idx >> 7, c = idx & 127;
      float s = 0.f;
      #pragma unroll
      for (int j = 0; j < 9; j++)
        s += wl[j*9 + i2] * (Zb[j*128 + c] + Zb[1152 + j*128 + c]);
      acc[idx] += s;
    }
  }

  __syncthreads();

  // ---- w_out projection ----
  {
    int o = tid;
    for (int i2 = 0; i2 < 9; i2++){
      int deg = d_DEG[i2];
      const float* wp = w_out + (size_t)deg*32768 + o;   // (3,128,256)
      float s = (i2==0) ? b_out[o] : 0.f;
      #pragma unroll 4
      for (int c = 0; c < 128; c += 4){
        float4 a = *(const float4*)&acc[i2*128 + c];
        s += a.x*wp[(size_t)c*256] + a.y*wp[(size_t)(c+1)*256]
           + a.z*wp[(size_t)(c+2)*256] + a.w*wp[(size_t)(c+3)*256];
      }
      out[((size_t)n*9 + i2)*256 + o] = s;
    }
  }
}

// ---------------- host ----------------
extern "C" void kernel_launch(void* const* d_in, const int* in_sizes, int n_in,
                              void* d_out, int out_size, void* d_ws, size_t ws_size,
                              hipStream_t stream){
  const float* x     = (const float*)d_in[0];
  const float* attn  = (const float*)d_in[1];
  const float* wig   = (const float*)d_in[2];
  const float* tg    = (const float*)d_in[3];
  const float* fg    = (const float*)d_in[4];
  const float* w_in  = (const float*)d_in[5];
  const float* b_in  = (const float*)d_in[6];
  const float* w_out = (const float*)d_in[7];
  const float* b_out = (const float*)d_in[8];
  const float* es    = (const float*)d_in[9];
  const float* et    = (const float*)d_in[10];
  const float* fdw   = (const float*)d_in[11];
  const float* fdb   = (const float*)d_in[12];
  const float* few   = (const float*)d_in[13];
  const float* feb   = (const float*)d_in[14];
  const float* d0w   = (const float*)d_in[15];
  const float* d0b   = (const float*)d_in[16];
  const float* m0w1  = (const float*)d_in[17];
  const float* m0w2  = (const float*)d_in[18];
  const float* m1dw  = (const float*)d_in[19];
  const float* m1db  = (const float*)d_in[20];
  const float* m1w1r = (const float*)d_in[21];
  const float* m1w2r = (const float*)d_in[22];
  const float* m1w1i = (const float*)d_in[23];
  const float* m1w2i = (const float*)d_in[24];
  const float* m2dw  = (const float*)d_in[25];
  const float* m2db  = (const float*)d_in[26];
  const float* m2w1r = (const float*)d_in[27];
  const float* m2w2r = (const float*)d_in[28];
  const float* m2w1i = (const float*)d_in[29];
  const float* m2w2i = (const float*)d_in[30];
  const int*   an    = (const int*)d_in[31];
  const int*   esrc  = (const int*)d_in[32];
  const void*  maskp = d_in[33];

  float* W  = (float*)d_ws;
  int* FLAG = (int*)d_ws;
  float* Hg  = W + 16;               // 589824 floats
  float* XEg = W + 16 + 589824;      // 65536 floats
  size_t need = (size_t)(16 + 589824 + 65536) * 4;
  int pre = (ws_size >= need) ? 1 : 0;

  k_detect<<<1,256,0,stream>>>((const unsigned int*)maskp, FLAG);
  if (pre){
    k_h<<<dim3(32,9),128,0,stream>>>(x, w_in, b_in, Hg);
    k_xe<<<16,256,0,stream>>>(attn, fdw, fdb, few, feb, es, et, an, esrc, XEg);
  }
  k_mega<<<512,256,0,stream>>>(
      x, w_in, b_in, attn, fdw, fdb, few, feb, es, et, an, esrc,
      d0w, d0b, m1dw, m1db, m2dw, m2db,
      m0w1, m0w2, m1w1r, m1w2r, m1w1i, m1w2i, m2w1r, m2w2r, m2w1i, m2w2i,
      wig, tg, fg, w_out, b_out, maskp, FLAG, Hg, XEg, pre, (float*)d_out);
}

// Round 6
// 581.134 us; speedup vs baseline: 2.2932x; 2.2932x over previous
//
#include <hip/hip_runtime.h>
#include <math.h>

__device__ const int d_PERM[9] = {0,2,6,3,7,1,5,8,4};
__device__ const int d_DEG[9]  = {0,1,1,1,2,2,2,2,2};

__device__ __forceinline__ float silu_f(float x){ return x / (1.0f + __expf(-x)); }

// flag: 0 = int32 words, 1 = u8 bytes, 2 = float32 words, 3 = int64 (low word)
__device__ __forceinline__ int mask_at(const void* mp, int flag, int e){
  if (flag==1) return ((const unsigned char*)mp)[e] != 0;
  if (flag==3) return ((const unsigned int*)mp)[2*e] != 0u;
  return ((const unsigned int*)mp)[e] != 0u;
}

__global__ void k_detect(const unsigned int* __restrict__ w, int* __restrict__ flag){
  __shared__ int notI, notF, anyOdd, anyEven;
  if (threadIdx.x==0){ notI=0; notF=0; anyOdd=0; anyEven=0; }
  __syncthreads();
  int li=0, lf=0, lo=0, le=0;
  for (int i = threadIdx.x; i < 1024; i += 256){
    unsigned int v = w[i];
    if (v != 0u && v != 1u) li = 1;
    if (v != 0u && v != 0x3F800000u) lf = 1;
    if (v != 0u){ if (i & 1) lo = 1; else le = 1; }
  }
  if (li) atomicOr(&notI,1);
  if (lf) atomicOr(&notF,1);
  if (lo) atomicOr(&anyOdd,1);
  if (le) atomicOr(&anyEven,1);
  __syncthreads();
  if (threadIdx.x==0){
    int f;
    if (!notI) f = (anyOdd || !anyEven) ? 0 : 3;
    else       f = (!notF) ? 2 : 1;
    *flag = f;
  }
}

// ---------------- precompute H = x @ w_in[DEG] (+b_in at j==0), layout (N,9,128) ----------------
__global__ __launch_bounds__(128) void k_h(const float* __restrict__ x,
    const float* __restrict__ w_in, const float* __restrict__ b_in,
    float* __restrict__ H){
  __shared__ float xl[16][260];
  int i = blockIdx.y; int n0 = blockIdx.x*16;
  int deg = d_DEG[i];
  for (int idx = threadIdx.x; idx < 16*256; idx += 128){
    int r = idx >> 8, c = idx & 255;
    xl[r][c] = x[((size_t)(n0+r)*9 + i)*256 + c];
  }
  __syncthreads();
  int o = threadIdx.x;
  float acc[16];
  #pragma unroll
  for (int r=0;r<16;r++) acc[r]=0.f;
  const float* w = w_in + (size_t)deg*32768 + o;
  for (int c=0;c<256;c+=4){
    float w0=w[(size_t)c*128], w1=w[(size_t)(c+1)*128], w2=w[(size_t)(c+2)*128], w3=w[(size_t)(c+3)*128];
    #pragma unroll
    for (int r=0;r<16;r++){
      float4 xv4 = *(const float4*)&xl[r][c];
      acc[r] += xv4.x*w0 + xv4.y*w1 + xv4.z*w2 + xv4.w*w3;
    }
  }
  float bb = (i==0)? b_in[o] : 0.f;
  #pragma unroll
  for (int r=0;r<16;r++) H[((size_t)(n0+r)*9+i)*128+o] = acc[r]+bb;
}

// ---------------- precompute XE (E,16) ----------------
__global__ __launch_bounds__(256) void k_xe(const float* __restrict__ attn,
    const float* __restrict__ fdw, const float* __restrict__ fdb,
    const float* __restrict__ few, const float* __restrict__ feb,
    const float* __restrict__ es, const float* __restrict__ et,
    const int* __restrict__ an, const int* __restrict__ esrc,
    float* __restrict__ XE){
  int e = blockIdx.x*256 + threadIdx.x;
  float aw[32];
  #pragma unroll
  for (int k=0;k<32;k+=4){
    float4 v = *(const float4*)&attn[(size_t)e*32+k];
    aw[k]=v.x; aw[k+1]=v.y; aw[k+2]=v.z; aw[k+3]=v.w;
  }
  int src = esrc[e]; int tgt = e>>3;
  int za = an[src], zb = an[tgt];
  float v0[16];
  #pragma unroll
  for (int j=0;j<16;j++){
    float s = fdb[j] + es[(size_t)za*16+j] + et[(size_t)zb*16+j];
    #pragma unroll
    for (int k=0;k<32;k++) s += aw[k]*fdw[k*16+j];
    v0[j] = silu_f(s);
  }
  #pragma unroll
  for (int j=0;j<16;j++){
    float s = feb[j];
    #pragma unroll
    for (int k=0;k<16;k++) s += v0[k]*few[k*16+j];
    XE[(size_t)e*16+j] = silu_f(s);
  }
}

// ---- dot helpers ----
__device__ __forceinline__ float dotW(const float* __restrict__ A, const float* __restrict__ Wm, int K){
  float s = 0.f;
  #pragma unroll 4
  for (int i=0;i<K;i+=4){
    float4 a = *(const float4*)&A[i];
    s += a.x*Wm[(size_t)i*128] + a.y*Wm[(size_t)(i+1)*128]
       + a.z*Wm[(size_t)(i+2)*128] + a.w*Wm[(size_t)(i+3)*128];
  }
  return s;
}
__device__ __forceinline__ float dot2W(const float* __restrict__ P0, const float* __restrict__ P1,
    const float* __restrict__ W0, const float* __restrict__ W1, int ldw){
  float s = 0.f;
  #pragma unroll 4
  for (int k=0;k<128;k+=4){
    float4 a = *(const float4*)&P0[k];
    float4 b = *(const float4*)&P1[k];
    s += a.x*W0[(size_t)k*ldw] + a.y*W0[(size_t)(k+1)*ldw] + a.z*W0[(size_t)(k+2)*ldw] + a.w*W0[(size_t)(k+3)*ldw];
    s += b.x*W1[(size_t)k*ldw] + b.y*W1[(size_t)(k+1)*ldw] + b.z*W1[(size_t)(k+2)*ldw] + b.w*W1[(size_t)(k+3)*ldw];
  }
  return s;
}

// ================= per-edge kernel: one block per edge (verified mega math) =================
// LDS (floats): xs 0..1152 | xtl 1152..2304 | (Zb aliases 0..2304)
//               gg 2304..3584 (Yb aliases 2304..3456) | P 3584..5888 | wl 5888..5969 | xe16 5972..5988
__global__ __launch_bounds__(256) void k_edge(
    const float* __restrict__ Hg,     const float* __restrict__ XEg,
    const int*   __restrict__ esrc,
    const float* __restrict__ d0w,    const float* __restrict__ d0b,
    const float* __restrict__ m1dw,   const float* __restrict__ m1db,
    const float* __restrict__ m2dw,   const float* __restrict__ m2db,
    const float* __restrict__ m0w1,   const float* __restrict__ m0w2,
    const float* __restrict__ m1w1r,  const float* __restrict__ m1w2r,
    const float* __restrict__ m1w1i,  const float* __restrict__ m1w2i,
    const float* __restrict__ m2w1r,  const float* __restrict__ m2w2r,
    const float* __restrict__ m2w1i,  const float* __restrict__ m2w2i,
    const float* __restrict__ wig,    const float* __restrict__ tg,   const float* __restrict__ fg,
    const void*  __restrict__ maskp,  const int* __restrict__ flagp,
    float* __restrict__ R)
{
  __shared__ float S[5988];
  float* xs   = S;
  float* xtl  = S + 1152;
  float* Zb   = S;
  float* gg   = S + 2304;
  float* Yb   = S + 2304;
  float* P    = S + 3584;
  float* wl   = S + 5888;
  float* xe16 = S + 5972;

  const int e   = blockIdx.x;
  const int tid = threadIdx.x;
  if (mask_at(maskp, *flagp, e)) return;
  const int n   = e >> 3;
  const int src = esrc[e];

  // ---- A2: stage wl & xe16; rotate from precomputed H ----
  for (int i = tid; i < 81; i += 256) wl[i] = wig[(size_t)e*81 + i];
  if (tid < 16) xe16[tid] = XEg[(size_t)e*16 + tid];
  for (int idx = tid; idx < 1152; idx += 256){
    int p = idx >> 7, c = idx & 127;
    int ch = d_PERM[p];
    const float* wr = wig + (size_t)e*81 + ch*9;
    const float* hs = Hg + (size_t)src*1152 + c;
    const float* ht = Hg + (size_t)n*1152 + c;
    float s1 = 0.f, s2 = 0.f;
    #pragma unroll
    for (int j = 0; j < 9; j++){
      float wv = wr[j];
      s1 += wv * hs[j*128];
      s2 += wv * ht[j*128];
    }
    xs[idx]  = s1;
    xtl[idx] = s2;
  }
  __syncthreads();

  // ---- A3: gates gg[1280] ----
  for (int col = tid; col < 1280; col += 256){
    int b = col / 640, r = col % 640;
    const float* w; float bias; int ldw, c2;
    if (r < 128){       w = d0w  + (size_t)b*2048; c2 = r;     ldw = 128; bias = d0b[b*128 + c2]; }
    else if (r < 384){  w = m1dw + (size_t)b*4096; c2 = r-128; ldw = 256; bias = m1db[b*256 + c2]; }
    else {              w = m2dw + (size_t)b*4096; c2 = r-384; ldw = 256; bias = m2db[b*256 + c2]; }
    float s = bias;
    #pragma unroll
    for (int kk = 0; kk < 16; kk++) s += xe16[kk] * w[kk*ldw + c2];
    gg[col] = silu_f(s);
  }
  __syncthreads();

  // ---- A4: stage-1 P ----
  for (int o = tid; o < 2304; o += 256){
    float s;
    if (o < 256){
      int path = o >> 7, h = o & 127;
      s = dotW(path ? xtl : xs, m0w1 + (size_t)path*49152 + h, 384);
    } else if (o < 1280){
      int q = (o-256) >> 8; int rem = (o-256) & 255; int t = rem >> 7, h = rem & 127;
      const float* A  = ((q>=2) ? xtl : xs) + 384 + t*256;
      const float* Wm = ((q&1) ? m1w1i : m1w1r) + (size_t)((q>=2)?1:0)*32768 + h;
      s = dotW(A, Wm, 256);
    } else {
      int q = (o-1280) >> 8; int rem = (o-1280) & 255; int t = rem >> 7, h = rem & 127;
      const float* A  = ((q>=2) ? xtl : xs) + 896 + t*128;
      const float* Wm = ((q&1) ? m2w1i : m2w1r) + (size_t)((q>=2)?1:0)*16384 + h;
      s = dotW(A, Wm, 128);
    }
    P[o] = s;
  }
  __syncthreads();

  // ---- A5: gate P in place ----
  for (int o = tid; o < 2304; o += 256){
    int h = o & 127, goff;
    if (o < 256) goff = (o >> 7) ? 640 : 0;
    else if (o < 1280){ int q = (o-256) >> 8;  goff = 128 + (q&1)*128 + (q>>1)*640; }
    else              { int q = (o-1280) >> 8; goff = 384 + (q&1)*128 + (q>>1)*640; }
    P[o] *= gg[goff + h];
  }
  __syncthreads();

  // ---- A6: stage-2 -> Yb (orig channel order; Yb aliases gg which is now dead) ----
  for (int o = tid; o < 1152; o += 256){
    float s; int ch, c;
    if (o < 384){
      int g = o >> 7; c = o & 127;
      ch = (g==0) ? 0 : ((g==1) ? 2 : 6);
      const float* w0 = m0w2 + o;                  // (2,128,384)
      s = dot2W(P, P+128, w0, w0+49152, 384);
    } else if (o < 896){
      int om = o - 384; int tp = om >> 8; int col = om & 255;
      int g = col >> 7; c = col & 127;
      ch = tp ? (g ? 5 : 1) : (g ? 7 : 3);
      float sgn = tp ? 1.f : -1.f;
      const float* wr = m1w2r + col;               // (2,128,256)
      const float* wi = m1w2i + col;
      s = dot2W(P+256+tp*128,     P+768+tp*128,     wr, wr+32768, 256)
        + sgn * dot2W(P+512+(1-tp)*128, P+1024+(1-tp)*128, wi, wi+32768, 256);
    } else {
      int om = o - 896; int tp = om >> 7; c = om & 127;
      ch = tp ? 4 : 8;
      float sgn = tp ? 1.f : -1.f;
      const float* wr = m2w2r + c;                 // (2,128,128)
      const float* wi = m2w2i + c;
      s = dot2W(P+1280+tp*128,     P+1792+tp*128,     wr, wr+16384, 128)
        + sgn * dot2W(P+1536+(1-tp)*128, P+2048+(1-tp)*128, wi, wi+16384, 128);
    }
    Yb[ch*128 + c] = s;
  }
  __syncthreads();

  // ---- A7: grid (to_grid -> silu -> from_grid); Zb aliases xs/xtl (dead after A4) ----
  {
    int half = tid >> 7, c = tid & 127;
    float z[9];
    #pragma unroll
    for (int i = 0; i < 9; i++) z[i] = 0.f;
    float y[9];
    #pragma unroll
    for (int i = 0; i < 9; i++) y[i] = Yb[i*128 + c];
    int p0 = half*162, p1 = p0 + 162;
    #pragma unroll 2
    for (int p = p0; p < p1; p++){
      float gp = 0.f;
      #pragma unroll
      for (int i = 0; i < 9; i++) gp += tg[p*9 + i] * y[i];
      float s = silu_f(gp);
      #pragma unroll
      for (int i = 0; i < 9; i++) z[i] += fg[p*9 + i] * s;
    }
    #pragma unroll
    for (int i = 0; i < 9; i++) Zb[half*1152 + i*128 + c] = z[i];
  }
  __syncthreads();

  // ---- A8: final wigner-transpose -> R[e] ----
  for (int idx = tid; idx < 1152; idx += 256){
    int i2 = idx >> 7, c = idx & 127;
    float s = 0.f;
    #pragma unroll
    for (int j = 0; j < 9; j++)
      s += wl[j*9 + i2] * (Zb[j*128 + c] + Zb[1152 + j*128 + c]);
    R[(size_t)e*1152 + idx] = s;
  }
}

// ================= masked reduce + w_out projection: block per (i2, n) =================
__global__ __launch_bounds__(256) void k_redout(const float* __restrict__ R,
    const void* __restrict__ maskp, const int* __restrict__ flagp,
    const float* __restrict__ w_out, const float* __restrict__ b_out,
    float* __restrict__ out){
  __shared__ float sacc[128];
  int i2 = blockIdx.x; int n = blockIdx.y;
  int tid = threadIdx.x;
  int f = *flagp;
  if (tid < 128){
    float a = 0.f;
    for (int k = 0; k < 8; k++){
      int e = n*8 + k;
      if (!mask_at(maskp, f, e)) a += R[(size_t)e*1152 + i2*128 + tid];
    }
    sacc[tid] = a;
  }
  __syncthreads();
  int o = tid;
  int deg = d_DEG[i2];
  const float* wp = w_out + (size_t)deg*32768 + o;   // (3,128,256)
  float s = (i2==0) ? b_out[o] : 0.f;
  #pragma unroll 4
  for (int c = 0; c < 128; c += 4){
    float4 a = *(const float4*)&sacc[c];
    s += a.x*wp[(size_t)c*256] + a.y*wp[(size_t)(c+1)*256]
       + a.z*wp[(size_t)(c+2)*256] + a.w*wp[(size_t)(c+3)*256];
  }
  out[((size_t)n*9 + i2)*256 + o] = s;
}

// ================= fallback mega kernel (round-5, pass-verified) =================
__global__ __launch_bounds__(256) void k_mega(
    const float* __restrict__ x,      const float* __restrict__ w_in,  const float* __restrict__ b_in,
    const float* __restrict__ attn,
    const float* __restrict__ fdw,    const float* __restrict__ fdb,
    const float* __restrict__ few,    const float* __restrict__ feb,
    const float* __restrict__ es,     const float* __restrict__ et,
    const int*   __restrict__ an,     const int*   __restrict__ esrc,
    const float* __restrict__ d0w,    const float* __restrict__ d0b,
    const float* __restrict__ m1dw,   const float* __restrict__ m1db,
    const float* __restrict__ m2dw,   const float* __restrict__ m2db,
    const float* __restrict__ m0w1,   const float* __restrict__ m0w2,
    const float* __restrict__ m1w1r,  const float* __restrict__ m1w2r,
    const float* __restrict__ m1w1i,  const float* __restrict__ m1w2i,
    const float* __restrict__ m2w1r,  const float* __restrict__ m2w2r,
    const float* __restrict__ m2w1i,  const float* __restrict__ m2w2i,
    const float* __restrict__ wig,    const float* __restrict__ tg,   const float* __restrict__ fg,
    const float* __restrict__ w_out,  const float* __restrict__ b_out,
    const void*  __restrict__ maskp,  const int* __restrict__ flagp,
    const float* __restrict__ Hg,     const float* __restrict__ XEg,  int pre,
    float* __restrict__ out)
{
  __shared__ float S[7168];
  float* acc  = S;
  float* xs   = S + 1152;
  float* xtl  = S + 2304;
  float* Zb   = S + 1152;
  float* gg   = S + 3456;
  float* Yb   = S + 3456;
  float* P    = S + 4736;
  float* wl   = S + 7040;
  float* xe16 = S + 7124;
  float* xv   = S + 7140;

  const int n   = blockIdx.x;
  const int tid = threadIdx.x;
  const int f   = *flagp;

  for (int i = tid; i < 1152; i += 256) acc[i] = 0.f;

  for (int k = 0; k < 8; k++){
    int e = n*8 + k;
    if (mask_at(maskp, f, e)) continue;
    int src = esrc[e];

    __syncthreads();

    if (pre){
      for (int i = tid; i < 81; i += 256) wl[i] = wig[(size_t)e*81 + i];
      if (tid < 16) xe16[tid] = XEg[(size_t)e*16 + tid];
      for (int idx = tid; idx < 1152; idx += 256){
        int p = idx >> 7, c = idx & 127;
        int ch = d_PERM[p];
        const float* wr = wig + (size_t)e*81 + ch*9;
        const float* hs = Hg + (size_t)src*1152 + c;
        const float* ht = Hg + (size_t)n*1152 + c;
        float s1 = 0.f, s2 = 0.f;
        #pragma unroll
        for (int j = 0; j < 9; j++){
          float wv = wr[j];
          s1 += wv * hs[j*128];
          s2 += wv * ht[j*128];
        }
        xs[idx]  = s1;
        xtl[idx] = s2;
      }
    } else {
      for (int i = tid; i < 81; i += 256) wl[i] = wig[(size_t)e*81 + i];
      if (tid < 16){
        int j = tid;
        float s = fdb[j] + es[(size_t)an[src]*16 + j] + et[(size_t)an[n]*16 + j];
        for (int kk = 0; kk < 32; kk++) s += attn[(size_t)e*32 + kk] * fdw[kk*16 + j];
        xv[j] = silu_f(s);
      }
      for (int idx = tid; idx < 2304; idx += 256){
        int which = idx >= 1152;
        int lidx = idx - which*1152;
        int j = lidx >> 7, c = lidx & 127;
        int deg = d_DEG[j];
        const float* wp = w_in + (size_t)deg*32768 + c;
        const float* xp = x + ((size_t)(which ? n : src)*9 + j)*256;
        float s = (j==0) ? b_in[c] : 0.f;
        for (int cc = 0; cc < 256; cc++) s += xp[cc] * wp[cc*128];
        P[idx] = s;
      }
      __syncthreads();
      if (tid < 16){
        int j = tid;
        float s = feb[j];
        for (int kk = 0; kk < 16; kk++) s += xv[kk] * few[kk*16 + j];
        xe16[j] = silu_f(s);
      }
      for (int idx = tid; idx < 1152; idx += 256){
        int p = idx >> 7, c = idx & 127;
        int ch = d_PERM[p];
        float s1 = 0.f, s2 = 0.f;
        #pragma unroll
        for (int j = 0; j < 9; j++){
          float wv = wl[ch*9 + j];
          s1 += wv * P[j*128 + c];
          s2 += wv * P[1152 + j*128 + c];
        }
        xs[idx]  = s1;
        xtl[idx] = s2;
      }
    }
    __syncthreads();

    for (int col = tid; col < 1280; col += 256){
      int b = col / 640, r = col % 640;
      const float* w; float bias; int ldw, c2;
      if (r < 128){       w = d0w  + (size_t)b*2048; c2 = r;     ldw = 128; bias = d0b[b*128 + c2]; }
      else if (r < 384){  w = m1dw + (size_t)b*4096; c2 = r-128; ldw = 256; bias = m1db[b*256 + c2]; }
      else {              w = m2dw + (size_t)b*4096; c2 = r-384; ldw = 256; bias = m2db[b*256 + c2]; }
      float s = bias;
      #pragma unroll
      for (int kk = 0; kk < 16; kk++) s += xe16[kk] * w[kk*ldw + c2];
      gg[col] = silu_f(s);
    }
    __syncthreads();

    for (int o = tid; o < 2304; o += 256){
      float s;
      if (o < 256){
        int path = o >> 7, h = o & 127;
        s = dotW(path ? xtl : xs, m0w1 + (size_t)path*49152 + h, 384);
      } else if (o < 1280){
        int q = (o-256) >> 8; int rem = (o-256) & 255; int t = rem >> 7, h = rem & 127;
        const float* A  = ((q>=2) ? xtl : xs) + 384 + t*256;
        const float* Wm = ((q&1) ? m1w1i : m1w1r) + (size_t)((q>=2)?1:0)*32768 + h;
        s = dotW(A, Wm, 256);
      } else {
        int q = (o-1280) >> 8; int rem = (o-1280) & 255; int t = rem >> 7, h = rem & 127;
        const float* A  = ((q>=2) ? xtl : xs) + 896 + t*128;
        const float* Wm = ((q&1) ? m2w1i : m2w1r) + (size_t)((q>=2)?1:0)*16384 + h;
        s = dotW(A, Wm, 128);
      }
      P[o] = s;
    }
    __syncthreads();

    for (int o = tid; o < 2304; o += 256){
      int h = o & 127, goff;
      if (o < 256) goff = (o >> 7) ? 640 : 0;
      else if (o < 1280){ int q = (o-256) >> 8;  goff = 128 + (q&1)*128 + (q>>1)*640; }
      else              { int q = (o-1280) >> 8; goff = 384 + (q&1)*128 + (q>>1)*640; }
      P[o] *= gg[goff + h];
    }
    __syncthreads();

    for (int o = tid; o < 1152; o += 256){
      float s; int ch, c;
      if (o < 384){
        int g = o >> 7; c = o & 127;
        ch = (g==0) ? 0 : ((g==1) ? 2 : 6);
        const float* w0 = m0w2 + o;
        s = dot2W(P, P+128, w0, w0+49152, 384);
      } else if (o < 896){
        int om = o - 384; int tp = om >> 8; int col = om & 255;
        int g = col >> 7; c = col & 127;
        ch = tp ? (g ? 5 : 1) : (g ? 7 : 3);
        float sgn = tp ? 1.f : -1.f;
        const float* wr = m1w2r + col;
        const float* wi = m1w2i + col;
        s = dot2W(P+256+tp*128,     P+768+tp*128,     wr, wr+32768, 256)
          + sgn * dot2W(P+512+(1-tp)*128, P+1024+(1-tp)*128, wi, wi+32768, 256);
      } else {
        int om = o - 896; int tp = om >> 7; c = om & 127;
        ch = tp ? 4 : 8;
        float sgn = tp ? 1.f : -1.f;
        const float* wr = m2w2r + c;
        const float* wi = m2w2i + c;
        s = dot2W(P+1280+tp*128,     P+1792+tp*128,     wr, wr+16384, 128)
          + sgn * dot2W(P+1536+(1-tp)*128, P+2048+(1-tp)*128, wi, wi+16384, 128);
      }
      Yb[ch*128 + c] = s;
    }
    __syncthreads();

    {
      int half = tid >> 7, c = tid & 127;
      float z[9];
      #pragma unroll
      for (int i = 0; i < 9; i++) z[i] = 0.f;
      float y[9];
      #pragma unroll
      for (int i = 0; i < 9; i++) y[i] = Yb[i*128 + c];
      int p0 = half*162, p1 = p0 + 162;
      #pragma unroll 2
      for (int p = p0; p < p1; p++){
        float gp = 0.f;
        #pragma unroll
        for (int i = 0; i < 9; i++) gp += tg[p*9 + i] * y[i];
        float s = silu_f(gp);
        #pragma unroll
        for (int i = 0; i < 9; i++) z[i] += fg[p*9 + i] * s;
      }
      #pragma unroll
      for (int i = 0; i < 9; i++) Zb[half*1152 + i*128 + c] = z[i];
    }
    __syncthreads();

    for (int idx = tid; idx < 1152; idx += 256){
      int i2 = idx >> 7, c = idx & 127;
      float s = 0.f;
      #pragma unroll
      for (int j = 0; j < 9; j++)
        s += wl[j*9 + i2] * (Zb[j*128 + c] + Zb[1152 + j*128 + c]);
      acc[idx] += s;
    }
  }

  __syncthreads();

  {
    int o = tid;
    for (int i2 = 0; i2 < 9; i2++){
      int deg = d_DEG[i2];
      const float* wp = w_out + (size_t)deg*32768 + o;
      float s = (i2==0) ? b_out[o] : 0.f;
      #pragma unroll 4
      for (int c = 0; c < 128; c += 4){
        float4 a = *(const float4*)&acc[i2*128 + c];
        s += a.x*wp[(size_t)c*256] + a.y*wp[(size_t)(c+1)*256]
           + a.z*wp[(size_t)(c+2)*256] + a.w*wp[(size_t)(c+3)*256];
      }
      out[((size_t)n*9 + i2)*256 + o] = s;
    }
  }
}

// ---------------- host ----------------
extern "C" void kernel_launch(void* const* d_in, const int* in_sizes, int n_in,
                              void* d_out, int out_size, void* d_ws, size_t ws_size,
                              hipStream_t stream){
  const float* x     = (const float*)d_in[0];
  const float* attn  = (const float*)d_in[1];
  const float* wig   = (const float*)d_in[2];
  const float* tg    = (const float*)d_in[3];
  const float* fg    = (const float*)d_in[4];
  const float* w_in  = (const float*)d_in[5];
  const float* b_in  = (const float*)d_in[6];
  const float* w_out = (const float*)d_in[7];
  const float* b_out = (const float*)d_in[8];
  const float* es    = (const float*)d_in[9];
  const float* et    = (const float*)d_in[10];
  const float* fdw   = (const float*)d_in[11];
  const float* fdb   = (const float*)d_in[12];
  const float* few   = (const float*)d_in[13];
  const float* feb   = (const float*)d_in[14];
  const float* d0w   = (const float*)d_in[15];
  const float* d0b   = (const float*)d_in[16];
  const float* m0w1  = (const float*)d_in[17];
  const float* m0w2  = (const float*)d_in[18];
  const float* m1dw  = (const float*)d_in[19];
  const float* m1db  = (const float*)d_in[20];
  const float* m1w1r = (const float*)d_in[21];
  const float* m1w2r = (const float*)d_in[22];
  const float* m1w1i = (const float*)d_in[23];
  const float* m1w2i = (const float*)d_in[24];
  const float* m2dw  = (const float*)d_in[25];
  const float* m2db  = (const float*)d_in[26];
  const float* m2w1r = (const float*)d_in[27];
  const float* m2w2r = (const float*)d_in[28];
  const float* m2w1i = (const float*)d_in[29];
  const float* m2w2i = (const float*)d_in[30];
  const int*   an    = (const int*)d_in[31];
  const int*   esrc  = (const int*)d_in[32];
  const void*  maskp = d_in[33];

  float* W  = (float*)d_ws;
  int* FLAG = (int*)d_ws;
  float* Hg  = W + 16;                         // 589824 floats
  float* XEg = Hg + 589824;                    // 65536 floats
  float* Rg  = XEg + 65536;                    // 4718592 floats
  size_t need_pre  = (size_t)(16 + 589824 + 65536) * 4;
  size_t need_full = need_pre + (size_t)4718592 * 4;

  k_detect<<<1,256,0,stream>>>((const unsigned int*)maskp, FLAG);

  if (ws_size >= need_full){
    k_h<<<dim3(32,9),128,0,stream>>>(x, w_in, b_in, Hg);
    k_xe<<<16,256,0,stream>>>(attn, fdw, fdb, few, feb, es, et, an, esrc, XEg);
    k_edge<<<4096,256,0,stream>>>(
        Hg, XEg, esrc,
        d0w, d0b, m1dw, m1db, m2dw, m2db,
        m0w1, m0w2, m1w1r, m1w2r, m1w1i, m1w2i, m2w1r, m2w2r, m2w1i, m2w2i,
        wig, tg, fg, maskp, FLAG, Rg);
    k_redout<<<dim3(9,512),256,0,stream>>>(Rg, maskp, FLAG, w_out, b_out, (float*)d_out);
  } else {
    int pre = (ws_size >= need_pre) ? 1 : 0;
    if (pre){
      k_h<<<dim3(32,9),128,0,stream>>>(x, w_in, b_in, Hg);
      k_xe<<<16,256,0,stream>>>(attn, fdw, fdb, few, feb, es, et, an, esrc, XEg);
    }
    k_mega<<<512,256,0,stream>>>(
        x, w_in, b_in, attn, fdw, fdb, few, feb, es, et, an, esrc,
        d0w, d0b, m1dw, m1db, m2dw, m2db,
        m0w1, m0w2, m1w1r, m1w2r, m1w1i, m1w2i, m2w1r, m2w2r, m2w1i, m2w2i,
        wig, tg, fg, w_out, b_out, maskp, FLAG, Hg, XEg, pre, (float*)d_out);
  }
}

// Round 7
// 524.972 us; speedup vs baseline: 2.5386x; 1.1070x over previous
//
#include <hip/hip_runtime.h>
#include <math.h>

__device__ const int d_PERM[9] = {0,2,6,3,7,1,5,8,4};
__device__ const int d_DEG[9]  = {0,1,1,1,2,2,2,2,2};

__device__ __forceinline__ float silu_f(float x){ return x / (1.0f + __expf(-x)); }

// flag: 0 = int32 words, 1 = u8 bytes, 2 = float32 words, 3 = int64 (low word)
__device__ __forceinline__ int mask_at(const void* mp, int flag, int e){
  if (flag==1) return ((const unsigned char*)mp)[e] != 0;
  if (flag==3) return ((const unsigned int*)mp)[2*e] != 0u;
  return ((const unsigned int*)mp)[e] != 0u;
}

__global__ void k_detect(const unsigned int* __restrict__ w, int* __restrict__ flag){
  __shared__ int notI, notF, anyOdd, anyEven;
  if (threadIdx.x==0){ notI=0; notF=0; anyOdd=0; anyEven=0; }
  __syncthreads();
  int li=0, lf=0, lo=0, le=0;
  for (int i = threadIdx.x; i < 1024; i += 256){
    unsigned int v = w[i];
    if (v != 0u && v != 1u) li = 1;
    if (v != 0u && v != 0x3F800000u) lf = 1;
    if (v != 0u){ if (i & 1) lo = 1; else le = 1; }
  }
  if (li) atomicOr(&notI,1);
  if (lf) atomicOr(&notF,1);
  if (lo) atomicOr(&anyOdd,1);
  if (le) atomicOr(&anyEven,1);
  __syncthreads();
  if (threadIdx.x==0){
    int f;
    if (!notI) f = (anyOdd || !anyEven) ? 0 : 3;
    else       f = (!notF) ? 2 : 1;
    *flag = f;
  }
}

// ---------------- compact active edges: list + count ----------------
__global__ __launch_bounds__(256) void k_compact(const void* __restrict__ maskp,
    const int* __restrict__ flagp, int* __restrict__ list, int* __restrict__ count){
  __shared__ int cnt[256];
  __shared__ int offs[256];
  int f = *flagp;
  int tid = threadIdx.x;
  int base = tid*16;
  int c = 0;
  for (int i=0;i<16;i++) if (!mask_at(maskp, f, base+i)) c++;
  cnt[tid] = c;
  __syncthreads();
  if (tid==0){
    int r = 0;
    for (int i=0;i<256;i++){ offs[i] = r; r += cnt[i]; }
    *count = r;
  }
  __syncthreads();
  int w = offs[tid];
  for (int i=0;i<16;i++){
    int e = base+i;
    if (!mask_at(maskp, f, e)) list[w++] = e;
  }
}

// ---------------- precompute H = x @ w_in[DEG] (+b_in at j==0), layout (N,9,128) ----------------
__global__ __launch_bounds__(128) void k_h(const float* __restrict__ x,
    const float* __restrict__ w_in, const float* __restrict__ b_in,
    float* __restrict__ H){
  __shared__ float xl[16][260];
  int i = blockIdx.y; int n0 = blockIdx.x*16;
  int deg = d_DEG[i];
  for (int idx = threadIdx.x; idx < 16*256; idx += 128){
    int r = idx >> 8, c = idx & 255;
    xl[r][c] = x[((size_t)(n0+r)*9 + i)*256 + c];
  }
  __syncthreads();
  int o = threadIdx.x;
  float acc[16];
  #pragma unroll
  for (int r=0;r<16;r++) acc[r]=0.f;
  const float* w = w_in + (size_t)deg*32768 + o;
  for (int c=0;c<256;c+=4){
    float w0=w[(size_t)c*128], w1=w[(size_t)(c+1)*128], w2=w[(size_t)(c+2)*128], w3=w[(size_t)(c+3)*128];
    #pragma unroll
    for (int r=0;r<16;r++){
      float4 xv4 = *(const float4*)&xl[r][c];
      acc[r] += xv4.x*w0 + xv4.y*w1 + xv4.z*w2 + xv4.w*w3;
    }
  }
  float bb = (i==0)? b_in[o] : 0.f;
  #pragma unroll
  for (int r=0;r<16;r++) H[((size_t)(n0+r)*9+i)*128+o] = acc[r]+bb;
}

// ---------------- precompute XE (E,16) ----------------
__global__ __launch_bounds__(256) void k_xe(const float* __restrict__ attn,
    const float* __restrict__ fdw, const float* __restrict__ fdb,
    const float* __restrict__ few, const float* __restrict__ feb,
    const float* __restrict__ es, const float* __restrict__ et,
    const int* __restrict__ an, const int* __restrict__ esrc,
    float* __restrict__ XE){
  int e = blockIdx.x*256 + threadIdx.x;
  float aw[32];
  #pragma unroll
  for (int k=0;k<32;k+=4){
    float4 v = *(const float4*)&attn[(size_t)e*32+k];
    aw[k]=v.x; aw[k+1]=v.y; aw[k+2]=v.z; aw[k+3]=v.w;
  }
  int src = esrc[e]; int tgt = e>>3;
  int za = an[src], zb = an[tgt];
  float v0[16];
  #pragma unroll
  for (int j=0;j<16;j++){
    float s = fdb[j] + es[(size_t)za*16+j] + et[(size_t)zb*16+j];
    #pragma unroll
    for (int k=0;k<32;k++) s += aw[k]*fdw[k*16+j];
    v0[j] = silu_f(s);
  }
  #pragma unroll
  for (int j=0;j<16;j++){
    float s = feb[j];
    #pragma unroll
    for (int k=0;k<16;k++) s += v0[k]*few[k*16+j];
    XE[(size_t)e*16+j] = silu_f(s);
  }
}

// ---- dot helpers for fallback ----
__device__ __forceinline__ float dotW(const float* __restrict__ A, const float* __restrict__ Wm, int K){
  float s = 0.f;
  #pragma unroll 4
  for (int i=0;i<K;i+=4){
    float4 a = *(const float4*)&A[i];
    s += a.x*Wm[(size_t)i*128] + a.y*Wm[(size_t)(i+1)*128]
       + a.z*Wm[(size_t)(i+2)*128] + a.w*Wm[(size_t)(i+3)*128];
  }
  return s;
}
__device__ __forceinline__ float dot2W(const float* __restrict__ P0, const float* __restrict__ P1,
    const float* __restrict__ W0, const float* __restrict__ W1, int ldw){
  float s = 0.f;
  #pragma unroll 4
  for (int k=0;k<128;k+=4){
    float4 a = *(const float4*)&P0[k];
    float4 b = *(const float4*)&P1[k];
    s += a.x*W0[(size_t)k*ldw] + a.y*W0[(size_t)(k+1)*ldw] + a.z*W0[(size_t)(k+2)*ldw] + a.w*W0[(size_t)(k+3)*ldw];
    s += b.x*W1[(size_t)k*ldw] + b.y*W1[(size_t)(k+1)*ldw] + b.z*W1[(size_t)(k+2)*ldw] + b.w*W1[(size_t)(k+3)*ldw];
  }
  return s;
}

// ================= 3-edge kernel: one block per 3 ACTIVE edges =================
// LDS floats: xs 0..3456 | xt 3456..6912 | (Zb aliases 0..6912, 3*2304)
//             gg 6912..10752 (Yb aliases, 3*1152) | P 10752..17664 | wl 17664..17907 | xe 17920..17968
__global__ __launch_bounds__(256, 2) void k_edge3(
    const float* __restrict__ Hg,     const float* __restrict__ XEg,
    const int*   __restrict__ esrc,
    const float* __restrict__ d0w,    const float* __restrict__ d0b,
    const float* __restrict__ m1dw,   const float* __restrict__ m1db,
    const float* __restrict__ m2dw,   const float* __restrict__ m2db,
    const float* __restrict__ m0w1,   const float* __restrict__ m0w2,
    const float* __restrict__ m1w1r,  const float* __restrict__ m1w2r,
    const float* __restrict__ m1w1i,  const float* __restrict__ m1w2i,
    const float* __restrict__ m2w1r,  const float* __restrict__ m2w2r,
    const float* __restrict__ m2w1i,  const float* __restrict__ m2w2i,
    const float* __restrict__ wig,    const float* __restrict__ tg,   const float* __restrict__ fg,
    const int*   __restrict__ list,   const int* __restrict__ countp,
    float* __restrict__ R)
{
  __shared__ float S[17984];
  float* xsB = S;
  float* xtB = S + 3456;
  float* ZbB = S;            // alias xs/xt (dead after A4)
  float* ggB = S + 6912;
  float* YbB = S + 6912;     // alias gg (dead after A4 epilogue)
  float* PB  = S + 10752;
  float* wlB = S + 17664;
  float* xeB = S + 17920;

  const int cnt = *countp;
  const int base = blockIdx.x*3;
  if (base >= cnt) return;
  const int tid = threadIdx.x;
  int eid[3];
  #pragma unroll
  for (int i=0;i<3;i++){ int s2 = base+i; eid[i] = list[s2 < cnt ? s2 : cnt-1]; }

  // ---- A2: wl, xe, rotate from Hg (per edge) ----
  for (int eL=0; eL<3; eL++){
    int e = eid[eL];
    int n = e >> 3, src = esrc[e];
    for (int i = tid; i < 81; i += 256) wlB[eL*81+i] = wig[(size_t)e*81 + i];
    if (tid < 16) xeB[eL*16+tid] = XEg[(size_t)e*16 + tid];
    for (int idx = tid; idx < 1152; idx += 256){
      int p = idx >> 7, c = idx & 127;
      int ch = d_PERM[p];
      const float* wr = wig + (size_t)e*81 + ch*9;
      const float* hs = Hg + (size_t)src*1152 + c;
      const float* ht = Hg + (size_t)n*1152 + c;
      float s1 = 0.f, s2v = 0.f;
      #pragma unroll
      for (int j = 0; j < 9; j++){
        float wv = wr[j];
        s1  += wv * hs[j*128];
        s2v += wv * ht[j*128];
      }
      xsB[eL*1152+idx] = s1;
      xtB[eL*1152+idx] = s2v;
    }
  }
  __syncthreads();

  // ---- A3: gates (3 edges share weight loads) ----
  for (int col = tid; col < 1280; col += 256){
    int b = col / 640, r = col % 640;
    const float* w; float bias; int ldw, c2;
    if (r < 128){       w = d0w  + (size_t)b*2048; c2 = r;     ldw = 128; bias = d0b[b*128 + c2]; }
    else if (r < 384){  w = m1dw + (size_t)b*4096; c2 = r-128; ldw = 256; bias = m1db[b*256 + c2]; }
    else {              w = m2dw + (size_t)b*4096; c2 = r-384; ldw = 256; bias = m2db[b*256 + c2]; }
    float s0 = bias, s1 = bias, s2v = bias;
    #pragma unroll
    for (int kk = 0; kk < 16; kk++){
      float wv = w[kk*ldw + c2];
      s0  += xeB[kk]      * wv;
      s1  += xeB[16 + kk] * wv;
      s2v += xeB[32 + kk] * wv;
    }
    ggB[col]        = silu_f(s0);
    ggB[1280 + col] = silu_f(s1);
    ggB[2560 + col] = silu_f(s2v);
  }
  __syncthreads();

  // ---- A4: stage-1 + gate (weights reused across 3 edges) ----
  for (int o = tid; o < 2304; o += 256){
    const float* Wm; const float* Ab; int K, goffh;
    if (o < 256){
      int path = o >> 7, h = o & 127;
      Wm = m0w1 + (size_t)path*49152 + h;
      Ab = path ? xtB : xsB;
      K = 384; goffh = (path ? 640 : 0) + h;
    } else if (o < 1280){
      int q = (o-256) >> 8, rem = (o-256) & 255, t = rem >> 7, h = rem & 127;
      Wm = ((q&1) ? m1w1i : m1w1r) + (size_t)((q>=2)?1:0)*32768 + h;
      Ab = ((q>=2) ? xtB : xsB) + 384 + t*256;
      K = 256; goffh = 128 + (q&1)*128 + (q>>1)*640 + h;
    } else {
      int q = (o-1280) >> 8, rem = (o-1280) & 255, t = rem >> 7, h = rem & 127;
      Wm = ((q&1) ? m2w1i : m2w1r) + (size_t)((q>=2)?1:0)*16384 + h;
      Ab = ((q>=2) ? xtB : xsB) + 896 + t*128;
      K = 128; goffh = 384 + (q&1)*128 + (q>>1)*640 + h;
    }
    float a0=0.f, a1=0.f, a2=0.f;
    #pragma unroll 2
    for (int k2=0; k2<K; k2+=4){
      float w0=Wm[(size_t)k2*128], w1=Wm[(size_t)(k2+1)*128], w2=Wm[(size_t)(k2+2)*128], w3=Wm[(size_t)(k2+3)*128];
      float4 v0 = *(const float4*)&Ab[k2];
      float4 v1 = *(const float4*)&Ab[1152 + k2];
      float4 v2 = *(const float4*)&Ab[2304 + k2];
      a0 += v0.x*w0 + v0.y*w1 + v0.z*w2 + v0.w*w3;
      a1 += v1.x*w0 + v1.y*w1 + v1.z*w2 + v1.w*w3;
      a2 += v2.x*w0 + v2.y*w1 + v2.z*w2 + v2.w*w3;
    }
    PB[o]          = a0 * ggB[goffh];
    PB[2304 + o]   = a1 * ggB[1280 + goffh];
    PB[4608 + o]   = a2 * ggB[2560 + goffh];
  }
  __syncthreads();

  // ---- A6: stage-2 -> Yb (weights reused across 3 edges) ----
  for (int o = tid; o < 1152; o += 256){
    float a0=0.f, a1=0.f, a2=0.f; int ch, c;
    if (o < 384){
      int g = o >> 7; c = o & 127;
      ch = (g==0) ? 0 : ((g==1) ? 2 : 6);
      const float* w0 = m0w2 + o;                  // (2,128,384)
      #pragma unroll 2
      for (int k2=0; k2<128; k2+=4){
        float wa0=w0[(size_t)k2*384], wa1=w0[(size_t)(k2+1)*384], wa2=w0[(size_t)(k2+2)*384], wa3=w0[(size_t)(k2+3)*384];
        float wb0=w0[49152+(size_t)k2*384], wb1=w0[49152+(size_t)(k2+1)*384], wb2=w0[49152+(size_t)(k2+2)*384], wb3=w0[49152+(size_t)(k2+3)*384];
        #pragma unroll
        for (int eL=0; eL<3; eL++){
          float4 p0 = *(const float4*)&PB[eL*2304 + k2];
          float4 p1 = *(const float4*)&PB[eL*2304 + 128 + k2];
          float v = p0.x*wa0 + p0.y*wa1 + p0.z*wa2 + p0.w*wa3
                  + p1.x*wb0 + p1.y*wb1 + p1.z*wb2 + p1.w*wb3;
          if (eL==0) a0 += v; else if (eL==1) a1 += v; else a2 += v;
        }
      }
    } else if (o < 896){
      int om = o - 384, tp = om >> 8, col = om & 255, g = col >> 7; c = col & 127;
      ch = tp ? (g ? 5 : 1) : (g ? 7 : 3);
      float sgn = tp ? 1.f : -1.f;
      const float* wr = m1w2r + col;               // (2,128,256)
      const float* wi = m1w2i + col;
      int or0 = 256 + tp*128, or1 = 768 + tp*128;
      int oi0 = 512 + (1-tp)*128, oi1 = 1024 + (1-tp)*128;
      #pragma unroll 2
      for (int k2=0; k2<128; k2+=4){
        float ra0=wr[(size_t)k2*256], ra1=wr[(size_t)(k2+1)*256], ra2=wr[(size_t)(k2+2)*256], ra3=wr[(size_t)(k2+3)*256];
        float rb0=wr[32768+(size_t)k2*256], rb1=wr[32768+(size_t)(k2+1)*256], rb2=wr[32768+(size_t)(k2+2)*256], rb3=wr[32768+(size_t)(k2+3)*256];
        float ia0=wi[(size_t)k2*256], ia1=wi[(size_t)(k2+1)*256], ia2=wi[(size_t)(k2+2)*256], ia3=wi[(size_t)(k2+3)*256];
        float ib0=wi[32768+(size_t)k2*256], ib1=wi[32768+(size_t)(k2+1)*256], ib2=wi[32768+(size_t)(k2+2)*256], ib3=wi[32768+(size_t)(k2+3)*256];
        #pragma unroll
        for (int eL=0; eL<3; eL++){
          const float* Pe = PB + eL*2304;
          float4 pr0 = *(const float4*)&Pe[or0 + k2];
          float4 pr1 = *(const float4*)&Pe[or1 + k2];
          float4 pi0 = *(const float4*)&Pe[oi0 + k2];
          float4 pi1 = *(const float4*)&Pe[oi1 + k2];
          float v = pr0.x*ra0 + pr0.y*ra1 + pr0.z*ra2 + pr0.w*ra3
                  + pr1.x*rb0 + pr1.y*rb1 + pr1.z*rb2 + pr1.w*rb3
                  + sgn*(pi0.x*ia0 + pi0.y*ia1 + pi0.z*ia2 + pi0.w*ia3
                       + pi1.x*ib0 + pi1.y*ib1 + pi1.z*ib2 + pi1.w*ib3);
          if (eL==0) a0 += v; else if (eL==1) a1 += v; else a2 += v;
        }
      }
    } else {
      int om = o - 896, tp = om >> 7; c = om & 127;
      ch = tp ? 4 : 8;
      float sgn = tp ? 1.f : -1.f;
      const float* wr = m2w2r + c;                 // (2,128,128)
      const float* wi = m2w2i + c;
      int or0 = 1280 + tp*128, or1 = 1792 + tp*128;
      int oi0 = 1536 + (1-tp)*128, oi1 = 2048 + (1-tp)*128;
      #pragma unroll 2
      for (int k2=0; k2<128; k2+=4){
        float ra0=wr[(size_t)k2*128], ra1=wr[(size_t)(k2+1)*128], ra2=wr[(size_t)(k2+2)*128], ra3=wr[(size_t)(k2+3)*128];
        float rb0=wr[16384+(size_t)k2*128], rb1=wr[16384+(size_t)(k2+1)*128], rb2=wr[16384+(size_t)(k2+2)*128], rb3=wr[16384+(size_t)(k2+3)*128];
        float ia0=wi[(size_t)k2*128], ia1=wi[(size_t)(k2+1)*128], ia2=wi[(size_t)(k2+2)*128], ia3=wi[(size_t)(k2+3)*128];
        float ib0=wi[16384+(size_t)k2*128], ib1=wi[16384+(size_t)(k2+1)*128], ib2=wi[16384+(size_t)(k2+2)*128], ib3=wi[16384+(size_t)(k2+3)*128];
        #pragma unroll
        for (int eL=0; eL<3; eL++){
          const float* Pe = PB + eL*2304;
          float4 pr0 = *(const float4*)&Pe[or0 + k2];
          float4 pr1 = *(const float4*)&Pe[or1 + k2];
          float4 pi0 = *(const float4*)&Pe[oi0 + k2];
          float4 pi1 = *(const float4*)&Pe[oi1 + k2];
          float v = pr0.x*ra0 + pr0.y*ra1 + pr0.z*ra2 + pr0.w*ra3
                  + pr1.x*rb0 + pr1.y*rb1 + pr1.z*rb2 + pr1.w*rb3
                  + sgn*(pi0.x*ia0 + pi0.y*ia1 + pi0.z*ia2 + pi0.w*ia3
                       + pi1.x*ib0 + pi1.y*ib1 + pi1.z*ib2 + pi1.w*ib3);
          if (eL==0) a0 += v; else if (eL==1) a1 += v; else a2 += v;
        }
      }
    }
    YbB[ch*128 + c]          = a0;
    YbB[1152 + ch*128 + c]   = a1;
    YbB[2304 + ch*128 + c]   = a2;
  }
  __syncthreads();

  // ---- A7: grid (to_grid -> silu -> from_grid), per edge; Zb aliases xs/xt ----
  for (int eL=0; eL<3; eL++){
    int half = tid >> 7, c = tid & 127;
    float y[9];
    #pragma unroll
    for (int i = 0; i < 9; i++) y[i] = YbB[eL*1152 + i*128 + c];
    float z[9];
    #pragma unroll
    for (int i = 0; i < 9; i++) z[i] = 0.f;
    int p0 = half*162, p1 = p0 + 162;
    #pragma unroll 2
    for (int p = p0; p < p1; p++){
      float gp = 0.f;
      #pragma unroll
      for (int i = 0; i < 9; i++) gp += tg[p*9 + i] * y[i];
      float s = silu_f(gp);
      #pragma unroll
      for (int i = 0; i < 9; i++) z[i] += fg[p*9 + i] * s;
    }
    #pragma unroll
    for (int i = 0; i < 9; i++) ZbB[eL*2304 + half*1152 + i*128 + c] = z[i];
  }
  __syncthreads();

  // ---- A8: final wigner-transpose -> R[eid] ----
  for (int eL=0; eL<3; eL++){
    for (int idx = tid; idx < 1152; idx += 256){
      int i2 = idx >> 7, c = idx & 127;
      float s = 0.f;
      #pragma unroll
      for (int j = 0; j < 9; j++)
        s += wlB[eL*81 + j*9 + i2] * (ZbB[eL*2304 + j*128 + c] + ZbB[eL*2304 + 1152 + j*128 + c]);
      R[(size_t)eid[eL]*1152 + idx] = s;
    }
  }
}

// ================= masked reduce + w_out projection: block per (i2, n) =================
__global__ __launch_bounds__(256) void k_redout(const float* __restrict__ R,
    const void* __restrict__ maskp, const int* __restrict__ flagp,
    const float* __restrict__ w_out, const float* __restrict__ b_out,
    float* __restrict__ out){
  __shared__ float sacc[128];
  int i2 = blockIdx.x; int n = blockIdx.y;
  int tid = threadIdx.x;
  int f = *flagp;
  if (tid < 128){
    float a = 0.f;
    for (int k = 0; k < 8; k++){
      int e = n*8 + k;
      if (!mask_at(maskp, f, e)) a += R[(size_t)e*1152 + i2*128 + tid];
    }
    sacc[tid] = a;
  }
  __syncthreads();
  int o = tid;
  int deg = d_DEG[i2];
  const float* wp = w_out + (size_t)deg*32768 + o;   // (3,128,256)
  float s = (i2==0) ? b_out[o] : 0.f;
  #pragma unroll 4
  for (int c = 0; c < 128; c += 4){
    float4 a = *(const float4*)&sacc[c];
    s += a.x*wp[(size_t)c*256] + a.y*wp[(size_t)(c+1)*256]
       + a.z*wp[(size_t)(c+2)*256] + a.w*wp[(size_t)(c+3)*256];
  }
  out[((size_t)n*9 + i2)*256 + o] = s;
}

// ================= fallback mega kernel (round-5, pass-verified) =================
__global__ __launch_bounds__(256) void k_mega(
    const float* __restrict__ x,      const float* __restrict__ w_in,  const float* __restrict__ b_in,
    const float* __restrict__ attn,
    const float* __restrict__ fdw,    const float* __restrict__ fdb,
    const float* __restrict__ few,    const float* __restrict__ feb,
    const float* __restrict__ es,     const float* __restrict__ et,
    const int*   __restrict__ an,     const int*   __restrict__ esrc,
    const float* __restrict__ d0w,    const float* __restrict__ d0b,
    const float* __restrict__ m1dw,   const float* __restrict__ m1db,
    const float* __restrict__ m2dw,   const float* __restrict__ m2db,
    const float* __restrict__ m0w1,   const float* __restrict__ m0w2,
    const float* __restrict__ m1w1r,  const float* __restrict__ m1w2r,
    const float* __restrict__ m1w1i,  const float* __restrict__ m1w2i,
    const float* __restrict__ m2w1r,  const float* __restrict__ m2w2r,
    const float* __restrict__ m2w1i,  const float* __restrict__ m2w2i,
    const float* __restrict__ wig,    const float* __restrict__ tg,   const float* __restrict__ fg,
    const float* __restrict__ w_out,  const float* __restrict__ b_out,
    const void*  __restrict__ maskp,  const int* __restrict__ flagp,
    const float* __restrict__ Hg,     const float* __restrict__ XEg,  int pre,
    float* __restrict__ out)
{
  __shared__ float S[7168];
  float* acc  = S;
  float* xs   = S + 1152;
  float* xtl  = S + 2304;
  float* Zb   = S + 1152;
  float* gg   = S + 3456;
  float* Yb   = S + 3456;
  float* P    = S + 4736;
  float* wl   = S + 7040;
  float* xe16 = S + 7124;
  float* xv   = S + 7140;

  const int n   = blockIdx.x;
  const int tid = threadIdx.x;
  const int f   = *flagp;

  for (int i = tid; i < 1152; i += 256) acc[i] = 0.f;

  for (int k = 0; k < 8; k++){
    int e = n*8 + k;
    if (mask_at(maskp, f, e)) continue;
    int src = esrc[e];

    __syncthreads();

    if (pre){
      for (int i = tid; i < 81; i += 256) wl[i] = wig[(size_t)e*81 + i];
      if (tid < 16) xe16[tid] = XEg[(size_t)e*16 + tid];
      for (int idx = tid; idx < 1152; idx += 256){
        int p = idx >> 7, c = idx & 127;
        int ch = d_PERM[p];
        const float* wr = wig + (size_t)e*81 + ch*9;
        const float* hs = Hg + (size_t)src*1152 + c;
        const float* ht = Hg + (size_t)n*1152 + c;
        float s1 = 0.f, s2 = 0.f;
        #pragma unroll
        for (int j = 0; j < 9; j++){
          float wv = wr[j];
          s1 += wv * hs[j*128];
          s2 += wv * ht[j*128];
        }
        xs[idx]  = s1;
        xtl[idx] = s2;
      }
    } else {
      for (int i = tid; i < 81; i += 256) wl[i] = wig[(size_t)e*81 + i];
      if (tid < 16){
        int j = tid;
        float s = fdb[j] + es[(size_t)an[src]*16 + j] + et[(size_t)an[n]*16 + j];
        for (int kk = 0; kk < 32; kk++) s += attn[(size_t)e*32 + kk] * fdw[kk*16 + j];
        xv[j] = silu_f(s);
      }
      for (int idx = tid; idx < 2304; idx += 256){
        int which = idx >= 1152;
        int lidx = idx - which*1152;
        int j = lidx >> 7, c = lidx & 127;
        int deg = d_DEG[j];
        const float* wp = w_in + (size_t)deg*32768 + c;
        const float* xp = x + ((size_t)(which ? n : src)*9 + j)*256;
        float s = (j==0) ? b_in[c] : 0.f;
        for (int cc = 0; cc < 256; cc++) s += xp[cc] * wp[cc*128];
        P[idx] = s;
      }
      __syncthreads();
      if (tid < 16){
        int j = tid;
        float s = feb[j];
        for (int kk = 0; kk < 16; kk++) s += xv[kk] * few[kk*16 + j];
        xe16[j] = silu_f(s);
      }
      for (int idx = tid; idx < 1152; idx += 256){
        int p = idx >> 7, c = idx & 127;
        int ch = d_PERM[p];
        float s1 = 0.f, s2 = 0.f;
        #pragma unroll
        for (int j = 0; j < 9; j++){
          float wv = wl[ch*9 + j];
          s1 += wv * P[j*128 + c];
          s2 += wv * P[1152 + j*128 + c];
        }
        xs[idx]  = s1;
        xtl[idx] = s2;
      }
    }
    __syncthreads();

    for (int col = tid; col < 1280; col += 256){
      int b = col / 640, r = col % 640;
      const float* w; float bias; int ldw, c2;
      if (r < 128){       w = d0w  + (size_t)b*2048; c2 = r;     ldw = 128; bias = d0b[b*128 + c2]; }
      else if (r < 384){  w = m1dw + (size_t)b*4096; c2 = r-128; ldw = 256; bias = m1db[b*256 + c2]; }
      else {              w = m2dw + (size_t)b*4096; c2 = r-384; ldw = 256; bias = m2db[b*256 + c2]; }
      float s = bias;
      #pragma unroll
      for (int kk = 0; kk < 16; kk++) s += xe16[kk] * w[kk*ldw + c2];
      gg[col] = silu_f(s);
    }
    __syncthreads();

    for (int o = tid; o < 2304; o += 256){
      float s;
      if (o < 256){
        int path = o >> 7, h = o & 127;
        s = dotW(path ? xtl : xs, m0w1 + (size_t)path*49152 + h, 384);
      } else if (o < 1280){
        int q = (o-256) >> 8; int rem = (o-256) & 255; int t = rem >> 7, h = rem & 127;
        const float* A  = ((q>=2) ? xtl : xs) + 384 + t*256;
        const float* Wm = ((q&1) ? m1w1i : m1w1r) + (size_t)((q>=2)?1:0)*32768 + h;
        s = dotW(A, Wm, 256);
      } else {
        int q = (o-1280) >> 8; int rem = (o-1280) & 255; int t = rem >> 7, h = rem & 127;
        const float* A  = ((q>=2) ? xtl : xs) + 896 + t*128;
        const float* Wm = ((q&1) ? m2w1i : m2w1r) + (size_t)((q>=2)?1:0)*16384 + h;
        s = dotW(A, Wm, 128);
      }
      P[o] = s;
    }
    __syncthreads();

    for (int o = tid; o < 2304; o += 256){
      int h = o & 127, goff;
      if (o < 256) goff = (o >> 7) ? 640 : 0;
      else if (o < 1280){ int q = (o-256) >> 8;  goff = 128 + (q&1)*128 + (q>>1)*640; }
      else              { int q = (o-1280) >> 8; goff = 384 + (q&1)*128 + (q>>1)*640; }
      P[o] *= gg[goff + h];
    }
    __syncthreads();

    for (int o = tid; o < 1152; o += 256){
      float s; int ch, c;
      if (o < 384){
        int g = o >> 7; c = o & 127;
        ch = (g==0) ? 0 : ((g==1) ? 2 : 6);
        const float* w0 = m0w2 + o;
        s = dot2W(P, P+128, w0, w0+49152, 384);
      } else if (o < 896){
        int om = o - 384; int tp = om >> 8; int col = om & 255;
        int g = col >> 7; c = col & 127;
        ch = tp ? (g ? 5 : 1) : (g ? 7 : 3);
        float sgn = tp ? 1.f : -1.f;
        const float* wr = m1w2r + col;
        const float* wi = m1w2i + col;
        s = dot2W(P+256+tp*128,     P+768+tp*128,     wr, wr+32768, 256)
          + sgn * dot2W(P+512+(1-tp)*128, P+1024+(1-tp)*128, wi, wi+32768, 256);
      } else {
        int om = o - 896; int tp = om >> 7; c = om & 127;
        ch = tp ? 4 : 8;
        float sgn = tp ? 1.f : -1.f;
        const float* wr = m2w2r + c;
        const float* wi = m2w2i + c;
        s = dot2W(P+1280+tp*128,     P+1792+tp*128,     wr, wr+16384, 128)
          + sgn * dot2W(P+1536+(1-tp)*128, P+2048+(1-tp)*128, wi, wi+16384, 128);
      }
      Yb[ch*128 + c] = s;
    }
    __syncthreads();

    {
      int half = tid >> 7, c = tid & 127;
      float z[9];
      #pragma unroll
      for (int i = 0; i < 9; i++) z[i] = 0.f;
      float y[9];
      #pragma unroll
      for (int i = 0; i < 9; i++) y[i] = Yb[i*128 + c];
      int p0 = half*162, p1 = p0 + 162;
      #pragma unroll 2
      for (int p = p0; p < p1; p++){
        float gp = 0.f;
        #pragma unroll
        for (int i = 0; i < 9; i++) gp += tg[p*9 + i] * y[i];
        float s = silu_f(gp);
        #pragma unroll
        for (int i = 0; i < 9; i++) z[i] += fg[p*9 + i] * s;
      }
      #pragma unroll
      for (int i = 0; i < 9; i++) Zb[half*1152 + i*128 + c] = z[i];
    }
    __syncthreads();

    for (int idx = tid; idx < 1152; idx += 256){
      int i2 = idx >> 7, c = idx & 127;
      float s = 0.f;
      #pragma unroll
      for (int j = 0; j < 9; j++)
        s += wl[j*9 + i2] * (Zb[j*128 + c] + Zb[1152 + j*128 + c]);
      acc[idx] += s;
    }
  }

  __syncthreads();

  {
    int o = tid;
    for (int i2 = 0; i2 < 9; i2++){
      int deg = d_DEG[i2];
      const float* wp = w_out + (size_t)deg*32768 + o;
      float s = (i2==0) ? b_out[o] : 0.f;
      #pragma unroll 4
      for (int c = 0; c < 128; c += 4){
        float4 a = *(const float4*)&acc[i2*128 + c];
        s += a.x*wp[(size_t)c*256] + a.y*wp[(size_t)(c+1)*256]
           + a.z*wp[(size_t)(c+2)*256] + a.w*wp[(size_t)(c+3)*256];
      }
      out[((size_t)n*9 + i2)*256 + o] = s;
    }
  }
}

// ---------------- host ----------------
extern "C" void kernel_launch(void* const* d_in, const int* in_sizes, int n_in,
                              void* d_out, int out_size, void* d_ws, size_t ws_size,
                              hipStream_t stream){
  const float* x     = (const float*)d_in[0];
  const float* attn  = (const float*)d_in[1];
  const float* wig   = (const float*)d_in[2];
  const float* tg    = (const float*)d_in[3];
  const float* fg    = (const float*)d_in[4];
  const float* w_in  = (const float*)d_in[5];
  const float* b_in  = (const float*)d_in[6];
  const float* w_out = (const float*)d_in[7];
  const float* b_out = (const float*)d_in[8];
  const float* es    = (const float*)d_in[9];
  const float* et    = (const float*)d_in[10];
  const float* fdw   = (const float*)d_in[11];
  const float* fdb   = (const float*)d_in[12];
  const float* few   = (const float*)d_in[13];
  const float* feb   = (const float*)d_in[14];
  const float* d0w   = (const float*)d_in[15];
  const float* d0b   = (const float*)d_in[16];
  const float* m0w1  = (const float*)d_in[17];
  const float* m0w2  = (const float*)d_in[18];
  const float* m1dw  = (const float*)d_in[19];
  const float* m1db  = (const float*)d_in[20];
  const float* m1w1r = (const float*)d_in[21];
  const float* m1w2r = (const float*)d_in[22];
  const float* m1w1i = (const float*)d_in[23];
  const float* m1w2i = (const float*)d_in[24];
  const float* m2dw  = (const float*)d_in[25];
  const float* m2db  = (const float*)d_in[26];
  const float* m2w1r = (const float*)d_in[27];
  const float* m2w2r = (const float*)d_in[28];
  const float* m2w1i = (const float*)d_in[29];
  const float* m2w2i = (const float*)d_in[30];
  const int*   an    = (const int*)d_in[31];
  const int*   esrc  = (const int*)d_in[32];
  const void*  maskp = d_in[33];

  float* W   = (float*)d_ws;
  int*   ip  = (int*)d_ws;
  int* FLAG  = ip + 0;
  int* COUNT = ip + 1;
  int* LIST  = ip + 16;                        // 4096 ints -> ends at 4112
  float* Hg  = W + 4112;                       // 589824 floats
  float* XEg = Hg + 589824;                    // 65536 floats
  float* Rg  = XEg + 65536;                    // 4718592 floats
  size_t need_pre  = (size_t)(4112 + 589824 + 65536) * 4;
  size_t need_full = need_pre + (size_t)4718592 * 4;

  k_detect<<<1,256,0,stream>>>((const unsigned int*)maskp, FLAG);

  if (ws_size >= need_full){
    k_compact<<<1,256,0,stream>>>(maskp, FLAG, LIST, COUNT);
    k_h<<<dim3(32,9),128,0,stream>>>(x, w_in, b_in, Hg);
    k_xe<<<16,256,0,stream>>>(attn, fdw, fdb, few, feb, es, et, an, esrc, XEg);
    k_edge3<<<1366,256,0,stream>>>(
        Hg, XEg, esrc,
        d0w, d0b, m1dw, m1db, m2dw, m2db,
        m0w1, m0w2, m1w1r, m1w2r, m1w1i, m1w2i, m2w1r, m2w2r, m2w1i, m2w2i,
        wig, tg, fg, LIST, COUNT, Rg);
    k_redout<<<dim3(9,512),256,0,stream>>>(Rg, maskp, FLAG, w_out, b_out, (float*)d_out);
  } else {
    int pre = (ws_size >= need_pre) ? 1 : 0;
    if (pre){
      k_h<<<dim3(32,9),128,0,stream>>>(x, w_in, b_in, Hg);
      k_xe<<<16,256,0,stream>>>(attn, fdw, fdb, few, feb, es, et, an, esrc, XEg);
    }
    k_mega<<<512,256,0,stream>>>(
        x, w_in, b_in, attn, fdw, fdb, few, feb, es, et, an, esrc,
        d0w, d0b, m1dw, m1db, m2dw, m2db,
        m0w1, m0w2, m1w1r, m1w2r, m1w1i, m1w2i, m2w1r, m2w2r, m2w1i, m2w2i,
        wig, tg, fg, w_out, b_out, maskp, FLAG, Hg, XEg, pre, (float*)d_out);
  }
}

// Round 8
// 491.472 us; speedup vs baseline: 2.7116x; 1.0682x over previous
//
#include <hip/hip_runtime.h>
#include <math.h>

__device__ const int d_PERM[9] = {0,2,6,3,7,1,5,8,4};
__device__ const int d_DEG[9]  = {0,1,1,1,2,2,2,2,2};

__device__ __forceinline__ float silu_f(float x){ return x / (1.0f + __expf(-x)); }

// flag: 0 = int32 words, 1 = u8 bytes, 2 = float32 words, 3 = int64 (low word)
__device__ __forceinline__ int mask_at(const void* mp, int flag, int e){
  if (flag==1) return ((const unsigned char*)mp)[e] != 0;
  if (flag==3) return ((const unsigned int*)mp)[2*e] != 0u;
  return ((const unsigned int*)mp)[e] != 0u;
}

__global__ void k_detect(const unsigned int* __restrict__ w, int* __restrict__ flag){
  __shared__ int notI, notF, anyOdd, anyEven;
  if (threadIdx.x==0){ notI=0; notF=0; anyOdd=0; anyEven=0; }
  __syncthreads();
  int li=0, lf=0, lo=0, le=0;
  for (int i = threadIdx.x; i < 1024; i += 256){
    unsigned int v = w[i];
    if (v != 0u && v != 1u) li = 1;
    if (v != 0u && v != 0x3F800000u) lf = 1;
    if (v != 0u){ if (i & 1) lo = 1; else le = 1; }
  }
  if (li) atomicOr(&notI,1);
  if (lf) atomicOr(&notF,1);
  if (lo) atomicOr(&anyOdd,1);
  if (le) atomicOr(&anyEven,1);
  __syncthreads();
  if (threadIdx.x==0){
    int f;
    if (!notI) f = (anyOdd || !anyEven) ? 0 : 3;
    else       f = (!notF) ? 2 : 1;
    *flag = f;
  }
}

__global__ __launch_bounds__(256) void k_compact(const void* __restrict__ maskp,
    const int* __restrict__ flagp, int* __restrict__ list, int* __restrict__ count){
  __shared__ int cnt[256];
  __shared__ int offs[256];
  int f = *flagp;
  int tid = threadIdx.x;
  int base = tid*16;
  int c = 0;
  for (int i=0;i<16;i++) if (!mask_at(maskp, f, base+i)) c++;
  cnt[tid] = c;
  __syncthreads();
  if (tid==0){
    int r = 0;
    for (int i=0;i<256;i++){ offs[i] = r; r += cnt[i]; }
    *count = r;
  }
  __syncthreads();
  int w = offs[tid];
  for (int i=0;i<16;i++){
    int e = base+i;
    if (!mask_at(maskp, f, e)) list[w++] = e;
  }
}

// ---------------- precompute H = x @ w_in[DEG] (+b_in at j==0), layout (N,9,128) ----------------
__global__ __launch_bounds__(128) void k_h(const float* __restrict__ x,
    const float* __restrict__ w_in, const float* __restrict__ b_in,
    float* __restrict__ H){
  __shared__ float xl[16][260];
  int i = blockIdx.y; int n0 = blockIdx.x*16;
  int deg = d_DEG[i];
  for (int idx = threadIdx.x; idx < 16*256; idx += 128){
    int r = idx >> 8, c = idx & 255;
    xl[r][c] = x[((size_t)(n0+r)*9 + i)*256 + c];
  }
  __syncthreads();
  int o = threadIdx.x;
  float acc[16];
  #pragma unroll
  for (int r=0;r<16;r++) acc[r]=0.f;
  const float* w = w_in + (size_t)deg*32768 + o;
  for (int c=0;c<256;c+=4){
    float w0=w[(size_t)c*128], w1=w[(size_t)(c+1)*128], w2=w[(size_t)(c+2)*128], w3=w[(size_t)(c+3)*128];
    #pragma unroll
    for (int r=0;r<16;r++){
      float4 xv4 = *(const float4*)&xl[r][c];
      acc[r] += xv4.x*w0 + xv4.y*w1 + xv4.z*w2 + xv4.w*w3;
    }
  }
  float bb = (i==0)? b_in[o] : 0.f;
  #pragma unroll
  for (int r=0;r<16;r++) H[((size_t)(n0+r)*9+i)*128+o] = acc[r]+bb;
}

// ---------------- precompute XE (E,16) ----------------
__global__ __launch_bounds__(256) void k_xe(const float* __restrict__ attn,
    const float* __restrict__ fdw, const float* __restrict__ fdb,
    const float* __restrict__ few, const float* __restrict__ feb,
    const float* __restrict__ es, const float* __restrict__ et,
    const int* __restrict__ an, const int* __restrict__ esrc,
    float* __restrict__ XE){
  int e = blockIdx.x*256 + threadIdx.x;
  float aw[32];
  #pragma unroll
  for (int k=0;k<32;k+=4){
    float4 v = *(const float4*)&attn[(size_t)e*32+k];
    aw[k]=v.x; aw[k+1]=v.y; aw[k+2]=v.z; aw[k+3]=v.w;
  }
  int src = esrc[e]; int tgt = e>>3;
  int za = an[src], zb = an[tgt];
  float v0[16];
  #pragma unroll
  for (int j=0;j<16;j++){
    float s = fdb[j] + es[(size_t)za*16+j] + et[(size_t)zb*16+j];
    #pragma unroll
    for (int k=0;k<32;k++) s += aw[k]*fdw[k*16+j];
    v0[j] = silu_f(s);
  }
  #pragma unroll
  for (int j=0;j<16;j++){
    float s = feb[j];
    #pragma unroll
    for (int k=0;k<16;k++) s += v0[k]*few[k*16+j];
    XE[(size_t)e*16+j] = silu_f(s);
  }
}

// ================= phase A: A2 rotate + A3 gates + A4 stage-1 (+gate) -> Pg =================
// LDS floats: xs 0..2304 | xt 2304..4608 | gg 4608..7168 | wl 7168..7330 | xe 7332..7364
__global__ __launch_bounds__(256, 4) void k_pA(
    const float* __restrict__ Hg,     const float* __restrict__ XEg,
    const int*   __restrict__ esrc,
    const float* __restrict__ d0w,    const float* __restrict__ d0b,
    const float* __restrict__ m1dw,   const float* __restrict__ m1db,
    const float* __restrict__ m2dw,   const float* __restrict__ m2db,
    const float* __restrict__ m0w1,
    const float* __restrict__ m1w1r,  const float* __restrict__ m1w1i,
    const float* __restrict__ m2w1r,  const float* __restrict__ m2w1i,
    const float* __restrict__ wig,
    const int*   __restrict__ list,   const int* __restrict__ countp,
    float* __restrict__ Pg)
{
  __shared__ float S[7364];
  float* xsB = S;
  float* xtB = S + 2304;
  float* ggB = S + 4608;
  float* wlB = S + 7168;
  float* xeB = S + 7332;

  const int cnt = *countp;
  const int base = blockIdx.x*2;
  if (base >= cnt) return;
  const int tid = threadIdx.x;
  int sid[2], eid[2];
  #pragma unroll
  for (int i=0;i<2;i++){ int s2 = base+i; sid[i] = (s2 < cnt) ? s2 : cnt-1; eid[i] = list[sid[i]]; }

  // ---- A2: wl, xe, rotate from Hg ----
  #pragma unroll
  for (int eL=0; eL<2; eL++){
    int e = eid[eL];
    int n = e >> 3, src = esrc[e];
    for (int i = tid; i < 81; i += 256) wlB[eL*81+i] = wig[(size_t)e*81 + i];
    if (tid < 16) xeB[eL*16+tid] = XEg[(size_t)e*16 + tid];
    for (int idx = tid; idx < 1152; idx += 256){
      int p = idx >> 7, c = idx & 127;
      int ch = d_PERM[p];
      const float* wr = wig + (size_t)e*81 + ch*9;
      const float* hs = Hg + (size_t)src*1152 + c;
      const float* ht = Hg + (size_t)n*1152 + c;
      float s1 = 0.f, s2v = 0.f;
      #pragma unroll
      for (int j = 0; j < 9; j++){
        float wv = wr[j];
        s1  += wv * hs[j*128];
        s2v += wv * ht[j*128];
      }
      xsB[eL*1152+idx] = s1;
      xtB[eL*1152+idx] = s2v;
    }
  }
  __syncthreads();

  // ---- A3: gates (2 edges share weight loads) ----
  for (int col = tid; col < 1280; col += 256){
    int b = col / 640, r = col % 640;
    const float* w; float bias; int ldw, c2;
    if (r < 128){       w = d0w  + (size_t)b*2048; c2 = r;     ldw = 128; bias = d0b[b*128 + c2]; }
    else if (r < 384){  w = m1dw + (size_t)b*4096; c2 = r-128; ldw = 256; bias = m1db[b*256 + c2]; }
    else {              w = m2dw + (size_t)b*4096; c2 = r-384; ldw = 256; bias = m2db[b*256 + c2]; }
    float s0 = bias, s1 = bias;
    #pragma unroll
    for (int kk = 0; kk < 16; kk++){
      float wv = w[kk*ldw + c2];
      s0 += xeB[kk]      * wv;
      s1 += xeB[16 + kk] * wv;
    }
    ggB[col]        = silu_f(s0);
    ggB[1280 + col] = silu_f(s1);
  }
  __syncthreads();

  // ---- A4: stage-1 + gate -> Pg ----
  for (int o = tid; o < 2304; o += 256){
    const float* Wm; const float* Ab; int K, goffh;
    if (o < 256){
      int path = o >> 7, h = o & 127;
      Wm = m0w1 + (size_t)path*49152 + h;
      Ab = path ? xtB : xsB;
      K = 384; goffh = (path ? 640 : 0) + h;
    } else if (o < 1280){
      int q = (o-256) >> 8, rem = (o-256) & 255, t = rem >> 7, h = rem & 127;
      Wm = ((q&1) ? m1w1i : m1w1r) + (size_t)((q>=2)?1:0)*32768 + h;
      Ab = ((q>=2) ? xtB : xsB) + 384 + t*256;
      K = 256; goffh = 128 + (q&1)*128 + (q>>1)*640 + h;
    } else {
      int q = (o-1280) >> 8, rem = (o-1280) & 255, t = rem >> 7, h = rem & 127;
      Wm = ((q&1) ? m2w1i : m2w1r) + (size_t)((q>=2)?1:0)*16384 + h;
      Ab = ((q>=2) ? xtB : xsB) + 896 + t*128;
      K = 128; goffh = 384 + (q&1)*128 + (q>>1)*640 + h;
    }
    float a0=0.f, a1=0.f;
    #pragma unroll 4
    for (int k2=0; k2<K; k2+=4){
      float w0=Wm[(size_t)k2*128], w1=Wm[(size_t)(k2+1)*128], w2=Wm[(size_t)(k2+2)*128], w3=Wm[(size_t)(k2+3)*128];
      float4 v0 = *(const float4*)&Ab[k2];
      float4 v1 = *(const float4*)&Ab[1152 + k2];
      a0 += v0.x*w0 + v0.y*w1 + v0.z*w2 + v0.w*w3;
      a1 += v1.x*w0 + v1.y*w1 + v1.z*w2 + v1.w*w3;
    }
    Pg[(size_t)sid[0]*2304 + o] = a0 * ggB[goffh];
    Pg[(size_t)sid[1]*2304 + o] = a1 * ggB[1280 + goffh];
  }
}

// ================= phase B: A6 stage-2 + A7 grid + A8 -> R =================
// LDS floats: PB 0..4608 (Zb aliases) | Yb 4608..6912 | wl 6912..7074
__global__ __launch_bounds__(256, 4) void k_pB(
    const float* __restrict__ Pg,
    const float* __restrict__ m0w2,
    const float* __restrict__ m1w2r,  const float* __restrict__ m1w2i,
    const float* __restrict__ m2w2r,  const float* __restrict__ m2w2i,
    const float* __restrict__ wig,    const float* __restrict__ tg,   const float* __restrict__ fg,
    const int*   __restrict__ list,   const int* __restrict__ countp,
    float* __restrict__ R)
{
  __shared__ float S[7074];
  float* PB  = S;           // 2*2304
  float* ZbB = S;           // alias (PB dead after A6)
  float* YbB = S + 4608;    // 2*1152
  float* wlB = S + 6912;    // 2*81

  const int cnt = *countp;
  const int base = blockIdx.x*2;
  if (base >= cnt) return;
  const int tid = threadIdx.x;
  int sid[2], eid[2];
  #pragma unroll
  for (int i=0;i<2;i++){ int s2 = base+i; sid[i] = (s2 < cnt) ? s2 : cnt-1; eid[i] = list[sid[i]]; }

  // ---- stage P and wl ----
  #pragma unroll
  for (int eL=0; eL<2; eL++){
    const float* src = Pg + (size_t)sid[eL]*2304;
    for (int idx = tid; idx < 2304; idx += 256) PB[eL*2304 + idx] = src[idx];
    for (int i = tid; i < 81; i += 256) wlB[eL*81+i] = wig[(size_t)eid[eL]*81 + i];
  }
  __syncthreads();

  // ---- A6: stage-2 -> Yb (weights reused across 2 edges) ----
  for (int o = tid; o < 1152; o += 256){
    float a0=0.f, a1=0.f; int ch, c;
    if (o < 384){
      int g = o >> 7; c = o & 127;
      ch = (g==0) ? 0 : ((g==1) ? 2 : 6);
      const float* w0 = m0w2 + o;                  // (2,128,384)
      #pragma unroll 2
      for (int k2=0; k2<128; k2+=4){
        float wa0=w0[(size_t)k2*384], wa1=w0[(size_t)(k2+1)*384], wa2=w0[(size_t)(k2+2)*384], wa3=w0[(size_t)(k2+3)*384];
        float wb0=w0[49152+(size_t)k2*384], wb1=w0[49152+(size_t)(k2+1)*384], wb2=w0[49152+(size_t)(k2+2)*384], wb3=w0[49152+(size_t)(k2+3)*384];
        #pragma unroll
        for (int eL=0; eL<2; eL++){
          float4 p0 = *(const float4*)&PB[eL*2304 + k2];
          float4 p1 = *(const float4*)&PB[eL*2304 + 128 + k2];
          float v = p0.x*wa0 + p0.y*wa1 + p0.z*wa2 + p0.w*wa3
                  + p1.x*wb0 + p1.y*wb1 + p1.z*wb2 + p1.w*wb3;
          if (eL==0) a0 += v; else a1 += v;
        }
      }
    } else if (o < 896){
      int om = o - 384, tp = om >> 8, col = om & 255, g = col >> 7; c = col & 127;
      ch = tp ? (g ? 5 : 1) : (g ? 7 : 3);
      float sgn = tp ? 1.f : -1.f;
      const float* wr = m1w2r + col;               // (2,128,256)
      const float* wi = m1w2i + col;
      int or0 = 256 + tp*128, or1 = 768 + tp*128;
      int oi0 = 512 + (1-tp)*128, oi1 = 1024 + (1-tp)*128;
      #pragma unroll 2
      for (int k2=0; k2<128; k2+=4){
        float ra0=wr[(size_t)k2*256], ra1=wr[(size_t)(k2+1)*256], ra2=wr[(size_t)(k2+2)*256], ra3=wr[(size_t)(k2+3)*256];
        float rb0=wr[32768+(size_t)k2*256], rb1=wr[32768+(size_t)(k2+1)*256], rb2=wr[32768+(size_t)(k2+2)*256], rb3=wr[32768+(size_t)(k2+3)*256];
        float ia0=wi[(size_t)k2*256], ia1=wi[(size_t)(k2+1)*256], ia2=wi[(size_t)(k2+2)*256], ia3=wi[(size_t)(k2+3)*256];
        float ib0=wi[32768+(size_t)k2*256], ib1=wi[32768+(size_t)(k2+1)*256], ib2=wi[32768+(size_t)(k2+2)*256], ib3=wi[32768+(size_t)(k2+3)*256];
        #pragma unroll
        for (int eL=0; eL<2; eL++){
          const float* Pe = PB + eL*2304;
          float4 pr0 = *(const float4*)&Pe[or0 + k2];
          float4 pr1 = *(const float4*)&Pe[or1 + k2];
          float4 pi0 = *(const float4*)&Pe[oi0 + k2];
          float4 pi1 = *(const float4*)&Pe[oi1 + k2];
          float v = pr0.x*ra0 + pr0.y*ra1 + pr0.z*ra2 + pr0.w*ra3
                  + pr1.x*rb0 + pr1.y*rb1 + pr1.z*rb2 + pr1.w*rb3
                  + sgn*(pi0.x*ia0 + pi0.y*ia1 + pi0.z*ia2 + pi0.w*ia3
                       + pi1.x*ib0 + pi1.y*ib1 + pi1.z*ib2 + pi1.w*ib3);
          if (eL==0) a0 += v; else a1 += v;
        }
      }
    } else {
      int om = o - 896, tp = om >> 7; c = om & 127;
      ch = tp ? 4 : 8;
      float sgn = tp ? 1.f : -1.f;
      const float* wr = m2w2r + c;                 // (2,128,128)
      const float* wi = m2w2i + c;
      int or0 = 1280 + tp*128, or1 = 1792 + tp*128;
      int oi0 = 1536 + (1-tp)*128, oi1 = 2048 + (1-tp)*128;
      #pragma unroll 2
      for (int k2=0; k2<128; k2+=4){
        float ra0=wr[(size_t)k2*128], ra1=wr[(size_t)(k2+1)*128], ra2=wr[(size_t)(k2+2)*128], ra3=wr[(size_t)(k2+3)*128];
        float rb0=wr[16384+(size_t)k2*128], rb1=wr[16384+(size_t)(k2+1)*128], rb2=wr[16384+(size_t)(k2+2)*128], rb3=wr[16384+(size_t)(k2+3)*128];
        float ia0=wi[(size_t)k2*128], ia1=wi[(size_t)(k2+1)*128], ia2=wi[(size_t)(k2+2)*128], ia3=wi[(size_t)(k2+3)*128];
        float ib0=wi[16384+(size_t)k2*128], ib1=wi[16384+(size_t)(k2+1)*128], ib2=wi[16384+(size_t)(k2+2)*128], ib3=wi[16384+(size_t)(k2+3)*128];
        #pragma unroll
        for (int eL=0; eL<2; eL++){
          const float* Pe = PB + eL*2304;
          float4 pr0 = *(const float4*)&Pe[or0 + k2];
          float4 pr1 = *(const float4*)&Pe[or1 + k2];
          float4 pi0 = *(const float4*)&Pe[oi0 + k2];
          float4 pi1 = *(const float4*)&Pe[oi1 + k2];
          float v = pr0.x*ra0 + pr0.y*ra1 + pr0.z*ra2 + pr0.w*ra3
                  + pr1.x*rb0 + pr1.y*rb1 + pr1.z*rb2 + pr1.w*rb3
                  + sgn*(pi0.x*ia0 + pi0.y*ia1 + pi0.z*ia2 + pi0.w*ia3
                       + pi1.x*ib0 + pi1.y*ib1 + pi1.z*ib2 + pi1.w*ib3);
          if (eL==0) a0 += v; else a1 += v;
        }
      }
    }
    YbB[ch*128 + c]        = a0;
    YbB[1152 + ch*128 + c] = a1;
  }
  __syncthreads();

  // ---- A7: grid (to_grid -> silu -> from_grid); Zb aliases PB (dead) ----
  #pragma unroll
  for (int eL=0; eL<2; eL++){
    int half = tid >> 7, c = tid & 127;
    float y[9];
    #pragma unroll
    for (int i = 0; i < 9; i++) y[i] = YbB[eL*1152 + i*128 + c];
    float z[9];
    #pragma unroll
    for (int i = 0; i < 9; i++) z[i] = 0.f;
    int p0 = half*162, p1 = p0 + 162;
    #pragma unroll 2
    for (int p = p0; p < p1; p++){
      float gp = 0.f;
      #pragma unroll
      for (int i = 0; i < 9; i++) gp += tg[p*9 + i] * y[i];
      float s = silu_f(gp);
      #pragma unroll
      for (int i = 0; i < 9; i++) z[i] += fg[p*9 + i] * s;
    }
    #pragma unroll
    for (int i = 0; i < 9; i++) ZbB[eL*2304 + half*1152 + i*128 + c] = z[i];
  }
  __syncthreads();

  // ---- A8: final wigner-transpose -> R[eid] ----
  #pragma unroll
  for (int eL=0; eL<2; eL++){
    for (int idx = tid; idx < 1152; idx += 256){
      int i2 = idx >> 7, c = idx & 127;
      float s = 0.f;
      #pragma unroll
      for (int j = 0; j < 9; j++)
        s += wlB[eL*81 + j*9 + i2] * (ZbB[eL*2304 + j*128 + c] + ZbB[eL*2304 + 1152 + j*128 + c]);
      R[(size_t)eid[eL]*1152 + idx] = s;
    }
  }
}

// ================= masked reduce + w_out projection: block per (i2, n) =================
__global__ __launch_bounds__(256) void k_redout(const float* __restrict__ R,
    const void* __restrict__ maskp, const int* __restrict__ flagp,
    const float* __restrict__ w_out, const float* __restrict__ b_out,
    float* __restrict__ out){
  __shared__ float sacc[128];
  int i2 = blockIdx.x; int n = blockIdx.y;
  int tid = threadIdx.x;
  int f = *flagp;
  if (tid < 128){
    float a = 0.f;
    for (int k = 0; k < 8; k++){
      int e = n*8 + k;
      if (!mask_at(maskp, f, e)) a += R[(size_t)e*1152 + i2*128 + tid];
    }
    sacc[tid] = a;
  }
  __syncthreads();
  int o = tid;
  int deg = d_DEG[i2];
  const float* wp = w_out + (size_t)deg*32768 + o;   // (3,128,256)
  float s = (i2==0) ? b_out[o] : 0.f;
  #pragma unroll 4
  for (int c = 0; c < 128; c += 4){
    float4 a = *(const float4*)&sacc[c];
    s += a.x*wp[(size_t)c*256] + a.y*wp[(size_t)(c+1)*256]
       + a.z*wp[(size_t)(c+2)*256] + a.w*wp[(size_t)(c+3)*256];
  }
  out[((size_t)n*9 + i2)*256 + o] = s;
}

// ================= tier-3 fallback mega kernel (round-5, pass-verified) =================
__device__ __forceinline__ float dotW(const float* __restrict__ A, const float* __restrict__ Wm, int K){
  float s = 0.f;
  #pragma unroll 4
  for (int i=0;i<K;i+=4){
    float4 a = *(const float4*)&A[i];
    s += a.x*Wm[(size_t)i*128] + a.y*Wm[(size_t)(i+1)*128]
       + a.z*Wm[(size_t)(i+2)*128] + a.w*Wm[(size_t)(i+3)*128];
  }
  return s;
}
__device__ __forceinline__ float dot2W(const float* __restrict__ P0, const float* __restrict__ P1,
    const float* __restrict__ W0, const float* __restrict__ W1, int ldw){
  float s = 0.f;
  #pragma unroll 4
  for (int k=0;k<128;k+=4){
    float4 a = *(const float4*)&P0[k];
    float4 b = *(const float4*)&P1[k];
    s += a.x*W0[(size_t)k*ldw] + a.y*W0[(size_t)(k+1)*ldw] + a.z*W0[(size_t)(k+2)*ldw] + a.w*W0[(size_t)(k+3)*ldw];
    s += b.x*W1[(size_t)k*ldw] + b.y*W1[(size_t)(k+1)*ldw] + b.z*W1[(size_t)(k+2)*ldw] + b.w*W1[(size_t)(k+3)*ldw];
  }
  return s;
}

__global__ __launch_bounds__(256) void k_mega(
    const float* __restrict__ x,      const float* __restrict__ w_in,  const float* __restrict__ b_in,
    const float* __restrict__ attn,
    const float* __restrict__ fdw,    const float* __restrict__ fdb,
    const float* __restrict__ few,    const float* __restrict__ feb,
    const float* __restrict__ es,     const float* __restrict__ et,
    const int*   __restrict__ an,     const int*   __restrict__ esrc,
    const float* __restrict__ d0w,    const float* __restrict__ d0b,
    const float* __restrict__ m1dw,   const float* __restrict__ m1db,
    const float* __restrict__ m2dw,   const float* __restrict__ m2db,
    const float* __restrict__ m0w1,   const float* __restrict__ m0w2,
    const float* __restrict__ m1w1r,  const float* __restrict__ m1w2r,
    const float* __restrict__ m1w1i,  const float* __restrict__ m1w2i,
    const float* __restrict__ m2w1r,  const float* __restrict__ m2w2r,
    const float* __restrict__ m2w1i,  const float* __restrict__ m2w2i,
    const float* __restrict__ wig,    const float* __restrict__ tg,   const float* __restrict__ fg,
    const float* __restrict__ w_out,  const float* __restrict__ b_out,
    const void*  __restrict__ maskp,  const int* __restrict__ flagp,
    const float* __restrict__ Hg,     const float* __restrict__ XEg,  int pre,
    float* __restrict__ out)
{
  __shared__ float S[7168];
  float* acc  = S;
  float* xs   = S + 1152;
  float* xtl  = S + 2304;
  float* Zb   = S + 1152;
  float* gg   = S + 3456;
  float* Yb   = S + 3456;
  float* P    = S + 4736;
  float* wl   = S + 7040;
  float* xe16 = S + 7124;
  float* xv   = S + 7140;

  const int n   = blockIdx.x;
  const int tid = threadIdx.x;
  const int f   = *flagp;

  for (int i = tid; i < 1152; i += 256) acc[i] = 0.f;

  for (int k = 0; k < 8; k++){
    int e = n*8 + k;
    if (mask_at(maskp, f, e)) continue;
    int src = esrc[e];

    __syncthreads();

    if (pre){
      for (int i = tid; i < 81; i += 256) wl[i] = wig[(size_t)e*81 + i];
      if (tid < 16) xe16[tid] = XEg[(size_t)e*16 + tid];
      for (int idx = tid; idx < 1152; idx += 256){
        int p = idx >> 7, c = idx & 127;
        int ch = d_PERM[p];
        const float* wr = wig + (size_t)e*81 + ch*9;
        const float* hs = Hg + (size_t)src*1152 + c;
        const float* ht = Hg + (size_t)n*1152 + c;
        float s1 = 0.f, s2 = 0.f;
        #pragma unroll
        for (int j = 0; j < 9; j++){
          float wv = wr[j];
          s1 += wv * hs[j*128];
          s2 += wv * ht[j*128];
        }
        xs[idx]  = s1;
        xtl[idx] = s2;
      }
    } else {
      for (int i = tid; i < 81; i += 256) wl[i] = wig[(size_t)e*81 + i];
      if (tid < 16){
        int j = tid;
        float s = fdb[j] + es[(size_t)an[src]*16 + j] + et[(size_t)an[n]*16 + j];
        for (int kk = 0; kk < 32; kk++) s += attn[(size_t)e*32 + kk] * fdw[kk*16 + j];
        xv[j] = silu_f(s);
      }
      for (int idx = tid; idx < 2304; idx += 256){
        int which = idx >= 1152;
        int lidx = idx - which*1152;
        int j = lidx >> 7, c = lidx & 127;
        int deg = d_DEG[j];
        const float* wp = w_in + (size_t)deg*32768 + c;
        const float* xp = x + ((size_t)(which ? n : src)*9 + j)*256;
        float s = (j==0) ? b_in[c] : 0.f;
        for (int cc = 0; cc < 256; cc++) s += xp[cc] * wp[cc*128];
        P[idx] = s;
      }
      __syncthreads();
      if (tid < 16){
        int j = tid;
        float s = feb[j];
        for (int kk = 0; kk < 16; kk++) s += xv[kk] * few[kk*16 + j];
        xe16[j] = silu_f(s);
      }
      for (int idx = tid; idx < 1152; idx += 256){
        int p = idx >> 7, c = idx & 127;
        int ch = d_PERM[p];
        float s1 = 0.f, s2 = 0.f;
        #pragma unroll
        for (int j = 0; j < 9; j++){
          float wv = wl[ch*9 + j];
          s1 += wv * P[j*128 + c];
          s2 += wv * P[1152 + j*128 + c];
        }
        xs[idx]  = s1;
        xtl[idx] = s2;
      }
    }
    __syncthreads();

    for (int col = tid; col < 1280; col += 256){
      int b = col / 640, r = col % 640;
      const float* w; float bias; int ldw, c2;
      if (r < 128){       w = d0w  + (size_t)b*2048; c2 = r;     ldw = 128; bias = d0b[b*128 + c2]; }
      else if (r < 384){  w = m1dw + (size_t)b*4096; c2 = r-128; ldw = 256; bias = m1db[b*256 + c2]; }
      else {              w = m2dw + (size_t)b*4096; c2 = r-384; ldw = 256; bias = m2db[b*256 + c2]; }
      float s = bias;
      #pragma unroll
      for (int kk = 0; kk < 16; kk++) s += xe16[kk] * w[kk*ldw + c2];
      gg[col] = silu_f(s);
    }
    __syncthreads();

    for (int o = tid; o < 2304; o += 256){
      float s;
      if (o < 256){
        int path = o >> 7, h = o & 127;
        s = dotW(path ? xtl : xs, m0w1 + (size_t)path*49152 + h, 384);
      } else if (o < 1280){
        int q = (o-256) >> 8; int rem = (o-256) & 255; int t = rem >> 7, h = rem & 127;
        const float* A  = ((q>=2) ? xtl : xs) + 384 + t*256;
        const float* Wm = ((q&1) ? m1w1i : m1w1r) + (size_t)((q>=2)?1:0)*32768 + h;
        s = dotW(A, Wm, 256);
      } else {
        int q = (o-1280) >> 8; int rem = (o-1280) & 255; int t = rem >> 7, h = rem & 127;
        const float* A  = ((q>=2) ? xtl : xs) + 896 + t*128;
        const float* Wm = ((q&1) ? m2w1i : m2w1r) + (size_t)((q>=2)?1:0)*16384 + h;
        s = dotW(A, Wm, 128);
      }
      P[o] = s;
    }
    __syncthreads();

    for (int o = tid; o < 2304; o += 256){
      int h = o & 127, goff;
      if (o < 256) goff = (o >> 7) ? 640 : 0;
      else if (o < 1280){ int q = (o-256) >> 8;  goff = 128 + (q&1)*128 + (q>>1)*640; }
      else              { int q = (o-1280) >> 8; goff = 384 + (q&1)*128 + (q>>1)*640; }
      P[o] *= gg[goff + h];
    }
    __syncthreads();

    for (int o = tid; o < 1152; o += 256){
      float s; int ch, c;
      if (o < 384){
        int g = o >> 7; c = o & 127;
        ch = (g==0) ? 0 : ((g==1) ? 2 : 6);
        const float* w0 = m0w2 + o;
        s = dot2W(P, P+128, w0, w0+49152, 384);
      } else if (o < 896){
        int om = o - 384; int tp = om >> 8; int col = om & 255;
        int g = col >> 7; c = col & 127;
        ch = tp ? (g ? 5 : 1) : (g ? 7 : 3);
        float sgn = tp ? 1.f : -1.f;
        const float* wr = m1w2r + col;
        const float* wi = m1w2i + col;
        s = dot2W(P+256+tp*128,     P+768+tp*128,     wr, wr+32768, 256)
          + sgn * dot2W(P+512+(1-tp)*128, P+1024+(1-tp)*128, wi, wi+32768, 256);
      } else {
        int om = o - 896; int tp = om >> 7; c = om & 127;
        ch = tp ? 4 : 8;
        float sgn = tp ? 1.f : -1.f;
        const float* wr = m2w2r + c;
        const float* wi = m2w2i + c;
        s = dot2W(P+1280+tp*128,     P+1792+tp*128,     wr, wr+16384, 128)
          + sgn * dot2W(P+1536+(1-tp)*128, P+2048+(1-tp)*128, wi, wi+16384, 128);
      }
      Yb[ch*128 + c] = s;
    }
    __syncthreads();

    {
      int half = tid >> 7, c = tid & 127;
      float z[9];
      #pragma unroll
      for (int i = 0; i < 9; i++) z[i] = 0.f;
      float y[9];
      #pragma unroll
      for (int i = 0; i < 9; i++) y[i] = Yb[i*128 + c];
      int p0 = half*162, p1 = p0 + 162;
      #pragma unroll 2
      for (int p = p0; p < p1; p++){
        float gp = 0.f;
        #pragma unroll
        for (int i = 0; i < 9; i++) gp += tg[p*9 + i] * y[i];
        float s = silu_f(gp);
        #pragma unroll
        for (int i = 0; i < 9; i++) z[i] += fg[p*9 + i] * s;
      }
      #pragma unroll
      for (int i = 0; i < 9; i++) Zb[half*1152 + i*128 + c] = z[i];
    }
    __syncthreads();

    for (int idx = tid; idx < 1152; idx += 256){
      int i2 = idx >> 7, c = idx & 127;
      float s = 0.f;
      #pragma unroll
      for (int j = 0; j < 9; j++)
        s += wl[j*9 + i2] * (Zb[j*128 + c] + Zb[1152 + j*128 + c]);
      acc[idx] += s;
    }
  }

  __syncthreads();

  {
    int o = tid;
    for (int i2 = 0; i2 < 9; i2++){
      int deg = d_DEG[i2];
      const float* wp = w_out + (size_t)deg*32768 + o;
      float s = (i2==0) ? b_out[o] : 0.f;
      #pragma unroll 4
      for (int c = 0; c < 128; c += 4){
        float4 a = *(const float4*)&acc[i2*128 + c];
        s += a.x*wp[(size_t)c*256] + a.y*wp[(size_t)(c+1)*256]
           + a.z*wp[(size_t)(c+2)*256] + a.w*wp[(size_t)(c+3)*256];
      }
      out[((size_t)n*9 + i2)*256 + o] = s;
    }
  }
}

// ================= tier-2 fallback: round-6 per-edge kernel (pass-verified, 24KB LDS) =========
__global__ __launch_bounds__(256) void k_edge(
    const float* __restrict__ Hg,     const float* __restrict__ XEg,
    const int*   __restrict__ esrc,
    const float* __restrict__ d0w,    const float* __restrict__ d0b,
    const float* __restrict__ m1dw,   const float* __restrict__ m1db,
    const float* __restrict__ m2dw,   const float* __restrict__ m2db,
    const float* __restrict__ m0w1,   const float* __restrict__ m0w2,
    const float* __restrict__ m1w1r,  const float* __restrict__ m1w2r,
    const float* __restrict__ m1w1i,  const float* __restrict__ m1w2i,
    const float* __restrict__ m2w1r,  const float* __restrict__ m2w2r,
    const float* __restrict__ m2w1i,  const float* __restrict__ m2w2i,
    const float* __restrict__ wig,    const float* __restrict__ tg,   const float* __restrict__ fg,
    const void*  __restrict__ maskp,  const int* __restrict__ flagp,
    float* __restrict__ R)
{
  __shared__ float S[5988];
  float* xs   = S;
  float* xtl  = S + 1152;
  float* Zb   = S;
  float* gg   = S + 2304;
  float* Yb   = S + 2304;
  float* P    = S + 3584;
  float* wl   = S + 5888;
  float* xe16 = S + 5972;

  const int e   = blockIdx.x;
  const int tid = threadIdx.x;
  if (mask_at(maskp, *flagp, e)) return;
  const int n   = e >> 3;
  const int src = esrc[e];

  for (int i = tid; i < 81; i += 256) wl[i] = wig[(size_t)e*81 + i];
  if (tid < 16) xe16[tid] = XEg[(size_t)e*16 + tid];
  for (int idx = tid; idx < 1152; idx += 256){
    int p = idx >> 7, c = idx & 127;
    int ch = d_PERM[p];
    const float* wr = wig + (size_t)e*81 + ch*9;
    const float* hs = Hg + (size_t)src*1152 + c;
    const float* ht = Hg + (size_t)n*1152 + c;
    float s1 = 0.f, s2 = 0.f;
    #pragma unroll
    for (int j = 0; j < 9; j++){
      float wv = wr[j];
      s1 += wv * hs[j*128];
      s2 += wv * ht[j*128];
    }
    xs[idx]  = s1;
    xtl[idx] = s2;
  }
  __syncthreads();

  for (int col = tid; col < 1280; col += 256){
    int b = col / 640, r = col % 640;
    const float* w; float bias; int ldw, c2;
    if (r < 128){       w = d0w  + (size_t)b*2048; c2 = r;     ldw = 128; bias = d0b[b*128 + c2]; }
    else if (r < 384){  w = m1dw + (size_t)b*4096; c2 = r-128; ldw = 256; bias = m1db[b*256 + c2]; }
    else {              w = m2dw + (size_t)b*4096; c2 = r-384; ldw = 256; bias = m2db[b*256 + c2]; }
    float s = bias;
    #pragma unroll
    for (int kk = 0; kk < 16; kk++) s += xe16[kk] * w[kk*ldw + c2];
    gg[col] = silu_f(s);
  }
  __syncthreads();

  for (int o = tid; o < 2304; o += 256){
    float s;
    if (o < 256){
      int path = o >> 7, h = o & 127;
      s = dotW(path ? xtl : xs, m0w1 + (size_t)path*49152 + h, 384);
    } else if (o < 1280){
      int q = (o-256) >> 8; int rem = (o-256) & 255; int t = rem >> 7, h = rem & 127;
      const float* A  = ((q>=2) ? xtl : xs) + 384 + t*256;
      const float* Wm = ((q&1) ? m1w1i : m1w1r) + (size_t)((q>=2)?1:0)*32768 + h;
      s = dotW(A, Wm, 256);
    } else {
      int q = (o-1280) >> 8; int rem = (o-1280) & 255; int t = rem >> 7, h = rem & 127;
      const float* A  = ((q>=2) ? xtl : xs) + 896 + t*128;
      const float* Wm = ((q&1) ? m2w1i : m2w1r) + (size_t)((q>=2)?1:0)*16384 + h;
      s = dotW(A, Wm, 128);
    }
    P[o] = s;
  }
  __syncthreads();

  for (int o = tid; o < 2304; o += 256){
    int h = o & 127, goff;
    if (o < 256) goff = (o >> 7) ? 640 : 0;
    else if (o < 1280){ int q = (o-256) >> 8;  goff = 128 + (q&1)*128 + (q>>1)*640; }
    else              { int q = (o-1280) >> 8; goff = 384 + (q&1)*128 + (q>>1)*640; }
    P[o] *= gg[goff + h];
  }
  __syncthreads();

  for (int o = tid; o < 1152; o += 256){
    float s; int ch, c;
    if (o < 384){
      int g = o >> 7; c = o & 127;
      ch = (g==0) ? 0 : ((g==1) ? 2 : 6);
      const float* w0 = m0w2 + o;
      s = dot2W(P, P+128, w0, w0+49152, 384);
    } else if (o < 896){
      int om = o - 384; int tp = om >> 8; int col = om & 255;
      int g = col >> 7; c = col & 127;
      ch = tp ? (g ? 5 : 1) : (g ? 7 : 3);
      float sgn = tp ? 1.f : -1.f;
      const float* wr = m1w2r + col;
      const float* wi = m1w2i + col;
      s = dot2W(P+256+tp*128,     P+768+tp*128,     wr, wr+32768, 256)
        + sgn * dot2W(P+512+(1-tp)*128, P+1024+(1-tp)*128, wi, wi+32768, 256);
    } else {
      int om = o - 896; int tp = om >> 7; c = om & 127;
      ch = tp ? 4 : 8;
      float sgn = tp ? 1.f : -1.f;
      const float* wr = m2w2r + c;
      const float* wi = m2w2i + c;
      s = dot2W(P+1280+tp*128,     P+1792+tp*128,     wr, wr+16384, 128)
        + sgn * dot2W(P+1536+(1-tp)*128, P+2048+(1-tp)*128, wi, wi+16384, 128);
    }
    Yb[ch*128 + c] = s;
  }
  __syncthreads();

  {
    int half = tid >> 7, c = tid & 127;
    float z[9];
    #pragma unroll
    for (int i = 0; i < 9; i++) z[i] = 0.f;
    float y[9];
    #pragma unroll
    for (int i = 0; i < 9; i++) y[i] = Yb[i*128 + c];
    int p0 = half*162, p1 = p0 + 162;
    #pragma unroll 2
    for (int p = p0; p < p1; p++){
      float gp = 0.f;
      #pragma unroll
      for (int i = 0; i < 9; i++) gp += tg[p*9 + i] * y[i];
      float s = silu_f(gp);
      #pragma unroll
      for (int i = 0; i < 9; i++) z[i] += fg[p*9 + i] * s;
    }
    #pragma unroll
    for (int i = 0; i < 9; i++) Zb[half*1152 + i*128 + c] = z[i];
  }
  __syncthreads();

  for (int idx = tid; idx < 1152; idx += 256){
    int i2 = idx >> 7, c = idx & 127;
    float s = 0.f;
    #pragma unroll
    for (int j = 0; j < 9; j++)
      s += wl[j*9 + i2] * (Zb[j*128 + c] + Zb[1152 + j*128 + c]);
    R[(size_t)e*1152 + idx] = s;
  }
}

// ---------------- host ----------------
extern "C" void kernel_launch(void* const* d_in, const int* in_sizes, int n_in,
                              void* d_out, int out_size, void* d_ws, size_t ws_size,
                              hipStream_t stream){
  const float* x     = (const float*)d_in[0];
  const float* attn  = (const float*)d_in[1];
  const float* wig   = (const float*)d_in[2];
  const float* tg    = (const float*)d_in[3];
  const float* fg    = (const float*)d_in[4];
  const float* w_in  = (const float*)d_in[5];
  const float* b_in  = (const float*)d_in[6];
  const float* w_out = (const float*)d_in[7];
  const float* b_out = (const float*)d_in[8];
  const float* es    = (const float*)d_in[9];
  const float* et    = (const float*)d_in[10];
  const float* fdw   = (const float*)d_in[11];
  const float* fdb   = (const float*)d_in[12];
  const float* few   = (const float*)d_in[13];
  const float* feb   = (const float*)d_in[14];
  const float* d0w   = (const float*)d_in[15];
  const float* d0b   = (const float*)d_in[16];
  const float* m0w1  = (const float*)d_in[17];
  const float* m0w2  = (const float*)d_in[18];
  const float* m1dw  = (const float*)d_in[19];
  const float* m1db  = (const float*)d_in[20];
  const float* m1w1r = (const float*)d_in[21];
  const float* m1w2r = (const float*)d_in[22];
  const float* m1w1i = (const float*)d_in[23];
  const float* m1w2i = (const float*)d_in[24];
  const float* m2dw  = (const float*)d_in[25];
  const float* m2db  = (const float*)d_in[26];
  const float* m2w1r = (const float*)d_in[27];
  const float* m2w2r = (const float*)d_in[28];
  const float* m2w1i = (const float*)d_in[29];
  const float* m2w2i = (const float*)d_in[30];
  const int*   an    = (const int*)d_in[31];
  const int*   esrc  = (const int*)d_in[32];
  const void*  maskp = d_in[33];

  float* W   = (float*)d_ws;
  int*   ip  = (int*)d_ws;
  int* FLAG  = ip + 0;
  int* COUNT = ip + 1;
  int* LIST  = ip + 16;                        // 4096 ints -> ends at 4112
  float* Hg  = W + 4112;                       // 589824
  float* XEg = Hg + 589824;                    // 65536
  float* Rg  = XEg + 65536;                    // 4718592
  float* Pg  = Rg + 4718592;                   // 9437184
  size_t need_pre = (size_t)(4112 + 589824 + 65536) * 4;
  size_t need_t2  = need_pre + (size_t)4718592 * 4;
  size_t need_t1  = need_t2 + (size_t)9437184 * 4;

  k_detect<<<1,256,0,stream>>>((const unsigned int*)maskp, FLAG);

  if (ws_size >= need_t1){
    k_compact<<<1,256,0,stream>>>(maskp, FLAG, LIST, COUNT);
    k_h<<<dim3(32,9),128,0,stream>>>(x, w_in, b_in, Hg);
    k_xe<<<16,256,0,stream>>>(attn, fdw, fdb, few, feb, es, et, an, esrc, XEg);
    k_pA<<<2048,256,0,stream>>>(
        Hg, XEg, esrc, d0w, d0b, m1dw, m1db, m2dw, m2db,
        m0w1, m1w1r, m1w1i, m2w1r, m2w1i,
        wig, LIST, COUNT, Pg);
    k_pB<<<2048,256,0,stream>>>(
        Pg, m0w2, m1w2r, m1w2i, m2w2r, m2w2i,
        wig, tg, fg, LIST, COUNT, Rg);
    k_redout<<<dim3(9,512),256,0,stream>>>(Rg, maskp, FLAG, w_out, b_out, (float*)d_out);
  } else if (ws_size >= need_t2){
    k_h<<<dim3(32,9),128,0,stream>>>(x, w_in, b_in, Hg);
    k_xe<<<16,256,0,stream>>>(attn, fdw, fdb, few, feb, es, et, an, esrc, XEg);
    k_edge<<<4096,256,0,stream>>>(
        Hg, XEg, esrc,
        d0w, d0b, m1dw, m1db, m2dw, m2db,
        m0w1, m0w2, m1w1r, m1w2r, m1w1i, m1w2i, m2w1r, m2w2r, m2w1i, m2w2i,
        wig, tg, fg, maskp, FLAG, Rg);
    k_redout<<<dim3(9,512),256,0,stream>>>(Rg, maskp, FLAG, w_out, b_out, (float*)d_out);
  } else {
    int pre = (ws_size >= need_pre) ? 1 : 0;
    if (pre){
      k_h<<<dim3(32,9),128,0,stream>>>(x, w_in, b_in, Hg);
      k_xe<<<16,256,0,stream>>>(attn, fdw, fdb, few, feb, es, et, an, esrc, XEg);
    }
    k_mega<<<512,256,0,stream>>>(
        x, w_in, b_in, attn, fdw, fdb, few, feb, es, et, an, esrc,
        d0w, d0b, m1dw, m1db, m2dw, m2db,
        m0w1, m0w2, m1w1r, m1w2r, m1w1i, m1w2i, m2w1r, m2w2r, m2w1i, m2w2i,
        wig, tg, fg, w_out, b_out, maskp, FLAG, Hg, XEg, pre, (float*)d_out);
  }
}